// Round 3
// baseline (1730.482 us; speedup 1.0000x reference)
//
#include <hip/hip_runtime.h>

typedef unsigned short u16;
typedef unsigned int   u32;
typedef __attribute__((ext_vector_type(8))) short short8;  // 8 x bf16 MFMA frag
typedef __attribute__((ext_vector_type(4))) float f32x4;   // MFMA accumulator

#define DI static __device__ __forceinline__

// ---- problem constants ----
// B=16, C=32, DW=64, H=256, W=256, HW=65536. ALL inputs fp32, output fp32.
// x3 intermediate (gated tensor, 16*32*65536 fp32 = 128 MiB) lives in d_out:
// k_front writes it, k_back consumes and overwrites with the final output.
//
// [R2: k_back rewritten around mfma_f32_16x16x32_bf16 (K=32 exact fit).
//  R1 counters: k_back 671 us, VALUBusy 37% but only 8% of cycles are the
//  core FMAs (4.5x issue overhead), Occ 25% -> latency-bound VALU conv.
//  Per 16-pixel group: 8 MFMAs replace ~4096 VALU FMAs. Weights persist in
//  VGPRs as bf16 B-frags; LN2 via shfl_xor over 16-lane groups; D->A
//  transposes through wave-private padded LDS (no barriers).
//  k_front/k_pack/k_sca byte-identical to the 1940.5 us verified baseline.]

// ---- workspace layout (float offsets); total ~445 KiB ----
static constexpr int OFF_SSUM = 0;        // 16*32 = 512
static constexpr int OFF_SCALE = 512;     // 512
static constexpr int OFF_W1 = 1024;       // 16*64*32 = 32768
static constexpr int OFF_B1 = 33792;      // 1024
static constexpr int OFF_W2 = 34816;      // 16*64*9 = 9216
static constexpr int OFF_B2 = 44032;      // 1024
static constexpr int OFF_W3 = 45056;      // 16*32*32 = 16384
static constexpr int OFF_B3 = 61440;      // 512
static constexpr int OFF_W4 = 61952;      // 32768
static constexpr int OFF_B4 = 94720;      // 1024
static constexpr int OFF_W5 = 95744;      // 16384
static constexpr int OFF_B5 = 112128;     // 512
static constexpr int OFF_N1W = 112640;    // 32
static constexpr int OFF_N1B = 112672;    // 32
static constexpr int OFF_N2W = 112704;    // 32
static constexpr int OFF_N2B = 112736;    // 32
static constexpr int OFF_SCAW = 112768;   // 1024
static constexpr int OFF_SCAB = 113792;   // 32
static constexpr int OFF_BETA = 113824;   // 32
static constexpr int OFF_GAMMA = 113856;  // 32  (end = 113888 floats)

DI u16 f2bf(float f) {
  u32 x = __float_as_uint(f);
  u32 r = (x + 0x7fffu + ((x >> 16) & 1u)) >> 16;  // RNE
  return (u16)r;
}

struct WPtrs {
  const float *w1, *b1, *w2, *b2, *w3, *b3, *w4, *b4, *w5, *b5;
  const float *n1w, *n1b, *n2w, *n2b, *scaw, *scab, *beta, *gamma;
};

DI void cpy_seg(float* dst, const float* src, int n, int tid, int stride) {
  for (int i = tid; i < n; i += stride) dst[i] = src[i];
}

// ---- K0: gather all weights into contiguous fp32 ws; zero SE accumulators ----
__global__ __launch_bounds__(256) void k_pack(WPtrs p, float* __restrict__ wf) {
  const int tid = blockIdx.x * 256 + threadIdx.x;
  const int stride = gridDim.x * 256;
  for (int i = tid; i < 512; i += stride) wf[OFF_SSUM + i] = 0.0f;
  cpy_seg(wf + OFF_W1, p.w1, 32768, tid, stride);
  cpy_seg(wf + OFF_B1, p.b1, 1024, tid, stride);
  cpy_seg(wf + OFF_W2, p.w2, 9216, tid, stride);
  cpy_seg(wf + OFF_B2, p.b2, 1024, tid, stride);
  cpy_seg(wf + OFF_W3, p.w3, 16384, tid, stride);
  cpy_seg(wf + OFF_B3, p.b3, 512, tid, stride);
  cpy_seg(wf + OFF_W4, p.w4, 32768, tid, stride);
  cpy_seg(wf + OFF_B4, p.b4, 1024, tid, stride);
  cpy_seg(wf + OFF_W5, p.w5, 16384, tid, stride);
  cpy_seg(wf + OFF_B5, p.b5, 512, tid, stride);
  cpy_seg(wf + OFF_N1W, p.n1w, 32, tid, stride);
  cpy_seg(wf + OFF_N1B, p.n1b, 32, tid, stride);
  cpy_seg(wf + OFF_N2W, p.n2w, 32, tid, stride);
  cpy_seg(wf + OFF_N2B, p.n2b, 32, tid, stride);
  cpy_seg(wf + OFF_SCAW, p.scaw, 1024, tid, stride);
  cpy_seg(wf + OFF_SCAB, p.scab, 32, tid, stride);
  cpy_seg(wf + OFF_BETA, p.beta, 32, tid, stride);
  cpy_seg(wf + OFF_GAMMA, p.gamma, 32, tid, stride);
}

// ---- K1: LN1 + conv1x1(32->64) + dwconv3x3 + SimpleGate -> x3 (fp32, in d_out);
// per-(b,c) channel sums for SE. Tile 32x8 interior, 34x10 with halo. Conv1 output
// kept in LDS as packed bf16 pairs (ch c lo16, ch c+32 hi16): one ds_read_b32
// yields both gate halves per tap.  [byte-identical to verified baseline]
__global__ __launch_bounds__(256) void k_front(const float* __restrict__ inp,
                                               const float* __restrict__ wf,
                                               float* __restrict__ x3,
                                               float* ssum) {
  const int tid = threadIdx.x;
  const int b = blockIdx.y;
  const int tile = blockIdx.x;        // 8 tiles in x, 32 in y
  const int tx = tile & 7, ty = tile >> 3;
  const int gx0 = tx * 32 - 1, gy0 = ty * 8 - 1;

  __shared__ u32 x1p[32][340];  // [pair][py*34+px]

  const float* w1 = wf + OFF_W1 + b * 2048;
  const float* b1 = wf + OFF_B1 + b * 64;
  const float* n1w = wf + OFF_N1W;
  const float* n1b = wf + OFF_N1B;

#pragma unroll 1
  for (int idx = tid; idx < 340; idx += 256) {
    const int py = idx / 34;
    const int px = idx - py * 34;
    const int gy = gy0 + py, gx = gx0 + px;
    if ((u32)gy >= 256u || (u32)gx >= 256u) {
#pragma unroll
      for (int c = 0; c < 32; c++) x1p[c][idx] = 0u;
    } else {
      const float* src = inp + (((size_t)(b * 32)) << 16) + (gy << 8) + gx;
      float x[32];
      float s = 0.f, s2 = 0.f;
#pragma unroll
      for (int c = 0; c < 32; c++) {
        float v = src[(size_t)c << 16];
        x[c] = v; s += v; s2 += v * v;
      }
      const float mu = s * (1.f / 32.f);
      const float var = fmaxf(s2 * (1.f / 32.f) - mu * mu, 0.f);
      const float rstd = rsqrtf(var + 1e-6f);
#pragma unroll
      for (int c = 0; c < 32; c++) x[c] = (x[c] - mu) * rstd * n1w[c] + n1b[c];
#pragma unroll
      for (int o = 0; o < 32; o++) {
        float a0 = b1[o], a1 = b1[o + 32];
#pragma unroll
        for (int c = 0; c < 32; c++) {
          a0 += x[c] * w1[o * 32 + c];
          a1 += x[c] * w1[(o + 32) * 32 + c];
        }
        x1p[o][idx] = (u32)f2bf(a0) | ((u32)f2bf(a1) << 16);
      }
    }
  }
  __syncthreads();

  const int px = tid & 31, py = tid >> 5;  // 32x8 interior
  const int p = (py + 1) * 34 + (px + 1);
  const int gpix = ((ty * 8 + py) << 8) + (tx * 32 + px);
  const float* w2 = wf + OFF_W2 + b * 576;
  const float* b2 = wf + OFF_B2 + b * 64;
  float* ob = x3 + (((size_t)(b * 32)) << 16) + gpix;
  float* sb = ssum + b * 32;

#pragma unroll 2
  for (int c = 0; c < 32; c++) {
    float a1 = b2[c], a2 = b2[c + 32];
    const int offs[9] = {-35, -34, -33, -1, 0, 1, 33, 34, 35};
#pragma unroll
    for (int k = 0; k < 9; k++) {
      const u32 u = x1p[c][p + offs[k]];
      const float lo = __uint_as_float(u << 16);
      const float hi = __uint_as_float(u & 0xffff0000u);
      a1 += lo * w2[c * 9 + k];
      a2 += hi * w2[(c + 32) * 9 + k];
    }
    const float v = a1 * a2;  // SimpleGate
    ob[(size_t)c << 16] = v;
    float r = v;
#pragma unroll
    for (int off = 32; off > 0; off >>= 1) r += __shfl_xor(r, off, 64);
    if ((tid & 63) == 0) atomicAdd(&sb[c], r);
  }
}

// ---- K2: SE head: mean -> 32x32 matmul -> per-(b,c) scale ----
__global__ __launch_bounds__(512) void k_sca(float* __restrict__ wf) {
  const int t = threadIdx.x;  // 512 = 16*32
  const int b = t >> 5, o = t & 31;
  const float* sw = wf + OFF_SCAW;
  float acc = wf[OFF_SCAB + o];
#pragma unroll
  for (int c = 0; c < 32; c++)
    acc += (wf[OFF_SSUM + b * 32 + c] * (1.f / 65536.f)) * sw[o * 32 + c];
  wf[OFF_SCALE + b * 32 + o] = acc;
}

// ---- K3 (MFMA): scale*x3 -> conv3 -> beta-res -> LN2 -> conv4 -> SG -> conv5
//                 -> gamma-res.  x3 and out are the SAME buffer (d_out); no
// __restrict__ on them. Each wave owns disjoint 16-pixel groups: all x3 reads
// of a group precede all out writes of that group in wave program order.
//
// MFMA geometry (mfma_f32_16x16x32_bf16, M=16 pix, N=16 outs, K=32 ch):
//   A-frag: lane l holds A[pix = l&15][c = 8*(l>>4)+j], j=0..7   (bf16x8)
//   B-frag: lane l holds B[c = 8*(l>>4)+j][o = l&15]  = W[o][c]  (bf16x8)
//   C/D   : lane l holds D[pix = 4*(l>>4)+r][o = l&15], r=0..3   (f32x4)
// Weights stay in VGPRs (8 frags = 32 VGPR). D->A transposes for conv4/conv5
// go through a wave-private LDS tile (16 pix x 40 u16, pad -> no b128 read
// conflicts; same-wave DS ordering, no barriers).
__global__ __launch_bounds__(256) void k_back(const float* __restrict__ inp,
                                              const float* x3,
                                              const float* __restrict__ wf,
                                              float* out) {
  const int tid = threadIdx.x;
  const int b = blockIdx.y;
  const int wv = tid >> 6;       // 4 waves/block
  const int lane = tid & 63;
  const int lr = lane & 15;
  const int lq = lane >> 4;

  __shared__ u16 tbuf[4][16][40];  // per-wave transpose tile (5120 B)

  const size_t ib = ((size_t)(b * 32)) << 16;
  const float* w3 = wf + OFF_W3 + b * 1024;
  const float* w4 = wf + OFF_W4 + b * 2048;
  const float* w5 = wf + OFF_W5 + b * 1024;

  // B-frags: lane reads W[o = t*16+lr][8*lq .. 8*lq+7], fp32 -> bf16 RNE
  short8 w3f[2], w4f[4], w5f[2];
#pragma unroll
  for (int t = 0; t < 2; t++) {
    const float* wp = w3 + (t * 16 + lr) * 32 + 8 * lq;
    short8 f;
#pragma unroll
    for (int j = 0; j < 8; j++) f[j] = (short)f2bf(wp[j]);
    w3f[t] = f;
  }
#pragma unroll
  for (int t = 0; t < 4; t++) {
    const float* wp = w4 + (t * 16 + lr) * 32 + 8 * lq;
    short8 f;
#pragma unroll
    for (int j = 0; j < 8; j++) f[j] = (short)f2bf(wp[j]);
    w4f[t] = f;
  }
#pragma unroll
  for (int t = 0; t < 2; t++) {
    const float* wp = w5 + (t * 16 + lr) * 32 + 8 * lq;
    short8 f;
#pragma unroll
    for (int j = 0; j < 8; j++) f[j] = (short)f2bf(wp[j]);
    w5f[t] = f;
  }

  float scv[8];  // SE scale for this lane's A-frag channels
#pragma unroll
  for (int j = 0; j < 8; j++) scv[j] = wf[OFF_SCALE + b * 32 + 8 * lq + j];

  float b3v[2], bev[2], n2wv[2], n2bv[2], b5v[2], gav[2], b4v[4];
#pragma unroll
  for (int t = 0; t < 2; t++) {
    b3v[t]  = wf[OFF_B3 + b * 32 + lr + 16 * t];
    bev[t]  = wf[OFF_BETA + lr + 16 * t];
    n2wv[t] = wf[OFF_N2W + lr + 16 * t];
    n2bv[t] = wf[OFF_N2B + lr + 16 * t];
    b5v[t]  = wf[OFF_B5 + b * 32 + lr + 16 * t];
    gav[t]  = wf[OFF_GAMMA + lr + 16 * t];
  }
#pragma unroll
  for (int t = 0; t < 4; t++) b4v[t] = wf[OFF_B4 + b * 64 + lr + 16 * t];

  const f32x4 zero = {0.f, 0.f, 0.f, 0.f};

#pragma unroll 1
  for (int it = 0; it < 4; it++) {
    const int P0 = blockIdx.x * 256 + wv * 64 + it * 16;

    // A-frag of SE-scaled x3: lane reads pix P0+lr at channels 8*lq+j
    short8 xaf;
#pragma unroll
    for (int j = 0; j < 8; j++) {
      float v = x3[ib + (((size_t)(8 * lq + j)) << 16) + P0 + lr] * scv[j];
      xaf[j] = (short)f2bf(v);
    }

    // conv3: 16 pix x 32 outs
    f32x4 d0 = __builtin_amdgcn_mfma_f32_16x16x32_bf16(xaf, w3f[0], zero, 0, 0, 0);
    f32x4 d1 = __builtin_amdgcn_mfma_f32_16x16x32_bf16(xaf, w3f[1], zero, 0, 0, 0);

    // y = inp + (conv3 + b3)*beta ; LN2 stats via 16-lane shfl_xor reduce
    float y[2][4], s[4], s2[4];
#pragma unroll
    for (int t = 0; t < 2; t++) {
      const f32x4 iv = *(const f32x4*)(inp + ib + (((size_t)(lr + 16 * t)) << 16) + P0 + 4 * lq);
      const f32x4 dd = t ? d1 : d0;
#pragma unroll
      for (int r = 0; r < 4; r++) y[t][r] = iv[r] + (dd[r] + b3v[t]) * bev[t];
    }
#pragma unroll
    for (int r = 0; r < 4; r++) {
      s[r]  = y[0][r] + y[1][r];
      s2[r] = y[0][r] * y[0][r] + y[1][r] * y[1][r];
    }
#pragma unroll
    for (int m = 1; m <= 8; m <<= 1) {
#pragma unroll
      for (int r = 0; r < 4; r++) {
        s[r]  += __shfl_xor(s[r], m, 64);
        s2[r] += __shfl_xor(s2[r], m, 64);
      }
    }
    float mu[4], rstd[4];
#pragma unroll
    for (int r = 0; r < 4; r++) {
      mu[r] = s[r] * (1.f / 32.f);
      const float var = fmaxf(s2[r] * (1.f / 32.f) - mu[r] * mu[r], 0.f);
      rstd[r] = rsqrtf(var + 1e-6f);
    }

    // z = LN2(y) -> bf16 -> LDS (D-layout write), read back as A-frag
#pragma unroll
    for (int t = 0; t < 2; t++) {
#pragma unroll
      for (int r = 0; r < 4; r++) {
        const float zz = (y[t][r] - mu[r]) * rstd[r] * n2wv[t] + n2bv[t];
        tbuf[wv][4 * lq + r][lr + 16 * t] = f2bf(zz);
      }
    }
    const short8 zf = *(const short8*)&tbuf[wv][lr][8 * lq];

    // conv4: 16 pix x 64 outs
    f32x4 e0 = __builtin_amdgcn_mfma_f32_16x16x32_bf16(zf, w4f[0], zero, 0, 0, 0);
    f32x4 e1 = __builtin_amdgcn_mfma_f32_16x16x32_bf16(zf, w4f[1], zero, 0, 0, 0);
    f32x4 e2 = __builtin_amdgcn_mfma_f32_16x16x32_bf16(zf, w4f[2], zero, 0, 0, 0);
    f32x4 e3 = __builtin_amdgcn_mfma_f32_16x16x32_bf16(zf, w4f[3], zero, 0, 0, 0);

    // SimpleGate: g[o] = (e[o]+b4[o]) * (e[o+32]+b4[o+32]) -> LDS -> A-frag
#pragma unroll
    for (int t = 0; t < 2; t++) {
      const f32x4 ea = t ? e1 : e0;
      const f32x4 eb = t ? e3 : e2;
#pragma unroll
      for (int r = 0; r < 4; r++) {
        const float gg = (ea[r] + b4v[t]) * (eb[r] + b4v[t + 2]);
        tbuf[wv][4 * lq + r][lr + 16 * t] = f2bf(gg);
      }
    }
    const short8 gf = *(const short8*)&tbuf[wv][lr][8 * lq];

    // conv5: 16 pix x 32 outs
    f32x4 f0 = __builtin_amdgcn_mfma_f32_16x16x32_bf16(gf, w5f[0], zero, 0, 0, 0);
    f32x4 f1 = __builtin_amdgcn_mfma_f32_16x16x32_bf16(gf, w5f[1], zero, 0, 0, 0);

    // out = y + (conv5 + b5)*gamma  (same D-layout as y -> float4 store)
#pragma unroll
    for (int t = 0; t < 2; t++) {
      const f32x4 ff = t ? f1 : f0;
      f32x4 ov;
#pragma unroll
      for (int r = 0; r < 4; r++) ov[r] = y[t][r] + (ff[r] + b5v[t]) * gav[t];
      *(f32x4*)(out + ib + (((size_t)(lr + 16 * t)) << 16) + P0 + 4 * lq) = ov;
    }
  }
}

extern "C" void kernel_launch(void* const* d_in, const int* in_sizes, int n_in,
                              void* d_out, int out_size, void* d_ws, size_t ws_size,
                              hipStream_t stream) {
  (void)in_sizes; (void)n_in; (void)out_size; (void)ws_size;
  const float* inp = (const float*)d_in[0];
  WPtrs p;
  p.w1 = (const float*)d_in[1];  p.b1 = (const float*)d_in[2];
  p.w2 = (const float*)d_in[3];  p.b2 = (const float*)d_in[4];
  p.w3 = (const float*)d_in[5];  p.b3 = (const float*)d_in[6];
  p.w4 = (const float*)d_in[7];  p.b4 = (const float*)d_in[8];
  p.w5 = (const float*)d_in[9];  p.b5 = (const float*)d_in[10];
  p.n1w = (const float*)d_in[11]; p.n1b = (const float*)d_in[12];
  p.n2w = (const float*)d_in[13]; p.n2b = (const float*)d_in[14];
  p.scaw = (const float*)d_in[15]; p.scab = (const float*)d_in[16];
  p.beta = (const float*)d_in[17]; p.gamma = (const float*)d_in[18];

  float* wf = (float*)d_ws;
  float* x3 = (float*)d_out;   // fp32 x3 lives in d_out (exact 128 MiB fit)
  float* out = (float*)d_out;

  k_pack<<<dim3(128), dim3(256), 0, stream>>>(p, wf);
  k_front<<<dim3(256, 16), dim3(256), 0, stream>>>(inp, wf, x3, wf + OFF_SSUM);
  k_sca<<<dim3(1), dim3(512), 0, stream>>>(wf);
  k_back<<<dim3(256, 16), dim3(256), 0, stream>>>(inp, x3, wf, out);
}

// Round 4
// 1559.508 us; speedup vs baseline: 1.1096x; 1.1096x over previous
//
#include <hip/hip_runtime.h>

typedef unsigned short u16;
typedef unsigned int   u32;
typedef __attribute__((ext_vector_type(8))) short short8;  // 8 x bf16 MFMA frag
typedef __attribute__((ext_vector_type(4))) float f32x4;   // MFMA accumulator

#define DI static __device__ __forceinline__

// ---- problem constants ----
// B=16, C=32, DW=64, H=256, W=256, HW=65536. ALL inputs fp32, output fp32.
// x3 intermediate (gated tensor, 128 MiB fp32) lives in d_out: k_front writes
// it, k_back consumes and overwrites with the final output.
//
// [R3: k_front conv1 moved to MFMA. R2 landed MFMA k_back (671 -> ~150 us) but
//  k_front regressed 1224 -> ~1550 us from co-compile codegen perturbation
//  (VGPR 116->68, VALUBusy 31->10%): conv1's 32-deep dependent VALU FMA chains
//  at ~2 waves/SIMD are pure latency. New k_front: (A) LN -> bf16 -> LDS tile,
//  (B) conv1 as 4 MFMAs per 16-pixel group (W1 in VGPR B-frags), D packed
//  straight into the x1p bf16-pair layout, (C) dwconv+gate+SE unchanged.]

// ---- workspace layout (float offsets); total ~445 KiB ----
static constexpr int OFF_SSUM = 0;        // 16*32 = 512
static constexpr int OFF_SCALE = 512;     // 512
static constexpr int OFF_W1 = 1024;       // 16*64*32 = 32768
static constexpr int OFF_B1 = 33792;      // 1024
static constexpr int OFF_W2 = 34816;      // 16*64*9 = 9216
static constexpr int OFF_B2 = 44032;      // 1024
static constexpr int OFF_W3 = 45056;      // 16*32*32 = 16384
static constexpr int OFF_B3 = 61440;      // 512
static constexpr int OFF_W4 = 61952;      // 32768
static constexpr int OFF_B4 = 94720;      // 1024
static constexpr int OFF_W5 = 95744;      // 16384
static constexpr int OFF_B5 = 112128;     // 512
static constexpr int OFF_N1W = 112640;    // 32
static constexpr int OFF_N1B = 112672;    // 32
static constexpr int OFF_N2W = 112704;    // 32
static constexpr int OFF_N2B = 112736;    // 32
static constexpr int OFF_SCAW = 112768;   // 1024
static constexpr int OFF_SCAB = 113792;   // 32
static constexpr int OFF_BETA = 113824;   // 32
static constexpr int OFF_GAMMA = 113856;  // 32  (end = 113888 floats)

DI u16 f2bf(float f) {
  u32 x = __float_as_uint(f);
  u32 r = (x + 0x7fffu + ((x >> 16) & 1u)) >> 16;  // RNE
  return (u16)r;
}

struct WPtrs {
  const float *w1, *b1, *w2, *b2, *w3, *b3, *w4, *b4, *w5, *b5;
  const float *n1w, *n1b, *n2w, *n2b, *scaw, *scab, *beta, *gamma;
};

DI void cpy_seg(float* dst, const float* src, int n, int tid, int stride) {
  for (int i = tid; i < n; i += stride) dst[i] = src[i];
}

// ---- K0: gather all weights into contiguous fp32 ws; zero SE accumulators ----
__global__ __launch_bounds__(256) void k_pack(WPtrs p, float* __restrict__ wf) {
  const int tid = blockIdx.x * 256 + threadIdx.x;
  const int stride = gridDim.x * 256;
  for (int i = tid; i < 512; i += stride) wf[OFF_SSUM + i] = 0.0f;
  cpy_seg(wf + OFF_W1, p.w1, 32768, tid, stride);
  cpy_seg(wf + OFF_B1, p.b1, 1024, tid, stride);
  cpy_seg(wf + OFF_W2, p.w2, 9216, tid, stride);
  cpy_seg(wf + OFF_B2, p.b2, 1024, tid, stride);
  cpy_seg(wf + OFF_W3, p.w3, 16384, tid, stride);
  cpy_seg(wf + OFF_B3, p.b3, 512, tid, stride);
  cpy_seg(wf + OFF_W4, p.w4, 32768, tid, stride);
  cpy_seg(wf + OFF_B4, p.b4, 1024, tid, stride);
  cpy_seg(wf + OFF_W5, p.w5, 16384, tid, stride);
  cpy_seg(wf + OFF_B5, p.b5, 512, tid, stride);
  cpy_seg(wf + OFF_N1W, p.n1w, 32, tid, stride);
  cpy_seg(wf + OFF_N1B, p.n1b, 32, tid, stride);
  cpy_seg(wf + OFF_N2W, p.n2w, 32, tid, stride);
  cpy_seg(wf + OFF_N2B, p.n2b, 32, tid, stride);
  cpy_seg(wf + OFF_SCAW, p.scaw, 1024, tid, stride);
  cpy_seg(wf + OFF_SCAB, p.scab, 32, tid, stride);
  cpy_seg(wf + OFF_BETA, p.beta, 32, tid, stride);
  cpy_seg(wf + OFF_GAMMA, p.gamma, 32, tid, stride);
}

// ---- K1: (A) LN1 -> bf16 LDS tile; (B) conv1x1(32->64) via MFMA; (C) dwconv3x3
// + SimpleGate -> x3 + SE channel sums.
// MFMA geometry (mfma_f32_16x16x32_bf16), per 16-pixel group g:
//   A-frag: lane l holds xln[pix = 16g + (l&15)][c = 8*(l>>4)+j]      (bf16x8)
//   B-frag: lane l holds W1[o = t*16 + (l&15)][c = 8*(l>>4)+j]        (bf16x8)
//   D     : lane l holds conv1[pix = 16g + 4*(l>>4)+r][o = t*16+(l&15)] (f32x4)
// D packs straight into x1p[c][pix] = (ch c lo16 | ch c+32 hi16) u32 pairs:
//   c = lr    <- (d0 + b1[lr],    d2 + b1[lr+32])
//   c = lr+16 <- (d1 + b1[lr+16], d3 + b1[lr+48])
__global__ __launch_bounds__(256) void k_front(const float* __restrict__ inp,
                                               const float* __restrict__ wf,
                                               float* __restrict__ x3,
                                               float* ssum) {
  const int tid = threadIdx.x;
  const int b = blockIdx.y;
  const int tile = blockIdx.x;        // 8 tiles in x, 32 in y
  const int tx = tile & 7, ty = tile >> 3;
  const int gx0 = tx * 32 - 1, gy0 = ty * 8 - 1;

  __shared__ u16 xln[352][40];   // LN'd input, bf16, pad-40 rows (28160 B)
  __shared__ u32 x1p[32][340];   // conv1 out, packed bf16 pairs  (43520 B)

  const float* w1 = wf + OFF_W1 + b * 2048;
  const float* b1 = wf + OFF_B1 + b * 64;
  const float* n1w = wf + OFF_N1W;
  const float* n1b = wf + OFF_N1B;

  // ---- stage A: LN per halo pixel -> bf16 -> xln ----
#pragma unroll 1
  for (int idx = tid; idx < 352; idx += 256) {
    const int py = idx / 34;
    const int px = idx - py * 34;
    const int gy = gy0 + py, gx = gx0 + px;
    u32 pk[16];
    if (idx >= 340 || (u32)gy >= 256u || (u32)gx >= 256u) {
#pragma unroll
      for (int j = 0; j < 16; j++) pk[j] = 0u;
    } else {
      const float* src = inp + (((size_t)(b * 32)) << 16) + (gy << 8) + gx;
      float x[32];
      float s = 0.f, s2 = 0.f;
#pragma unroll
      for (int c = 0; c < 32; c++) {
        float v = src[(size_t)c << 16];
        x[c] = v; s += v; s2 += v * v;
      }
      const float mu = s * (1.f / 32.f);
      const float var = fmaxf(s2 * (1.f / 32.f) - mu * mu, 0.f);
      const float rstd = rsqrtf(var + 1e-6f);
#pragma unroll
      for (int j = 0; j < 16; j++) {
        const float lo = (x[2 * j] - mu) * rstd * n1w[2 * j] + n1b[2 * j];
        const float hi = (x[2 * j + 1] - mu) * rstd * n1w[2 * j + 1] + n1b[2 * j + 1];
        pk[j] = (u32)f2bf(lo) | ((u32)f2bf(hi) << 16);
      }
    }
    u32* row = (u32*)&xln[idx][0];  // 80 B rows -> always 16B aligned
#pragma unroll
    for (int q = 0; q < 4; q++)
      *(uint4*)(row + 4 * q) = make_uint4(pk[4 * q], pk[4 * q + 1], pk[4 * q + 2], pk[4 * q + 3]);
  }

  // ---- W1 B-frags + biases (global loads, independent of stage A) ----
  const int lane = tid & 63;
  const int wv = tid >> 6;
  const int lr = lane & 15;
  const int lq = lane >> 4;

  short8 w1f[4];
#pragma unroll
  for (int t = 0; t < 4; t++) {
    const float* wp = w1 + (t * 16 + lr) * 32 + 8 * lq;
    short8 f;
#pragma unroll
    for (int j = 0; j < 8; j++) f[j] = (short)f2bf(wp[j]);
    w1f[t] = f;
  }
  float b1v[4];
#pragma unroll
  for (int t = 0; t < 4; t++) b1v[t] = b1[t * 16 + lr];

  __syncthreads();

  // ---- stage B: conv1 via MFMA, 22 groups of 16 pixels ----
  const f32x4 zero = {0.f, 0.f, 0.f, 0.f};
#pragma unroll 1
  for (int g = wv; g < 22; g += 4) {
    const short8 af = *(const short8*)&xln[16 * g + lr][8 * lq];
    f32x4 d0 = __builtin_amdgcn_mfma_f32_16x16x32_bf16(af, w1f[0], zero, 0, 0, 0);
    f32x4 d1 = __builtin_amdgcn_mfma_f32_16x16x32_bf16(af, w1f[1], zero, 0, 0, 0);
    f32x4 d2 = __builtin_amdgcn_mfma_f32_16x16x32_bf16(af, w1f[2], zero, 0, 0, 0);
    f32x4 d3 = __builtin_amdgcn_mfma_f32_16x16x32_bf16(af, w1f[3], zero, 0, 0, 0);
#pragma unroll
    for (int r = 0; r < 4; r++) {
      const int pix = 16 * g + 4 * lq + r;
      if (pix < 340) {
        const int py = pix / 34;
        const int px = pix - 34 * py;
        const int gy = gy0 + py, gx = gx0 + px;
        u32 v0 = 0u, v1 = 0u;
        if (((u32)gy < 256u) & ((u32)gx < 256u)) {
          v0 = (u32)f2bf(d0[r] + b1v[0]) | ((u32)f2bf(d2[r] + b1v[2]) << 16);
          v1 = (u32)f2bf(d1[r] + b1v[1]) | ((u32)f2bf(d3[r] + b1v[3]) << 16);
        }
        x1p[lr][pix] = v0;
        x1p[lr + 16][pix] = v1;
      }
    }
  }
  __syncthreads();

  // ---- stage C: dwconv3x3 + SimpleGate -> x3; SE channel sums ----
  const int px = tid & 31, py = tid >> 5;  // 32x8 interior
  const int p = (py + 1) * 34 + (px + 1);
  const int gpix = ((ty * 8 + py) << 8) + (tx * 32 + px);
  const float* w2 = wf + OFF_W2 + b * 576;
  const float* b2 = wf + OFF_B2 + b * 64;
  float* ob = x3 + (((size_t)(b * 32)) << 16) + gpix;
  float* sb = ssum + b * 32;

#pragma unroll 2
  for (int c = 0; c < 32; c++) {
    float a1 = b2[c], a2 = b2[c + 32];
    const int offs[9] = {-35, -34, -33, -1, 0, 1, 33, 34, 35};
#pragma unroll
    for (int k = 0; k < 9; k++) {
      const u32 u = x1p[c][p + offs[k]];
      const float lo = __uint_as_float(u << 16);
      const float hi = __uint_as_float(u & 0xffff0000u);
      a1 += lo * w2[c * 9 + k];
      a2 += hi * w2[(c + 32) * 9 + k];
    }
    const float v = a1 * a2;  // SimpleGate
    ob[(size_t)c << 16] = v;
    float r = v;
#pragma unroll
    for (int off = 32; off > 0; off >>= 1) r += __shfl_xor(r, off, 64);
    if ((tid & 63) == 0) atomicAdd(&sb[c], r);
  }
}

// ---- K2: SE head: mean -> 32x32 matmul -> per-(b,c) scale ----
__global__ __launch_bounds__(512) void k_sca(float* __restrict__ wf) {
  const int t = threadIdx.x;  // 512 = 16*32
  const int b = t >> 5, o = t & 31;
  const float* sw = wf + OFF_SCAW;
  float acc = wf[OFF_SCAB + o];
#pragma unroll
  for (int c = 0; c < 32; c++)
    acc += (wf[OFF_SSUM + b * 32 + c] * (1.f / 65536.f)) * sw[o * 32 + c];
  wf[OFF_SCALE + b * 32 + o] = acc;
}

// ---- K3 (MFMA): scale*x3 -> conv3 -> beta-res -> LN2 -> conv4 -> SG -> conv5
//                 -> gamma-res.  [unchanged from R2 verified version]
__global__ __launch_bounds__(256) void k_back(const float* __restrict__ inp,
                                              const float* x3,
                                              const float* __restrict__ wf,
                                              float* out) {
  const int tid = threadIdx.x;
  const int b = blockIdx.y;
  const int wv = tid >> 6;       // 4 waves/block
  const int lane = tid & 63;
  const int lr = lane & 15;
  const int lq = lane >> 4;

  __shared__ u16 tbuf[4][16][40];  // per-wave transpose tile (5120 B)

  const size_t ib = ((size_t)(b * 32)) << 16;
  const float* w3 = wf + OFF_W3 + b * 1024;
  const float* w4 = wf + OFF_W4 + b * 2048;
  const float* w5 = wf + OFF_W5 + b * 1024;

  // B-frags: lane reads W[o = t*16+lr][8*lq .. 8*lq+7], fp32 -> bf16 RNE
  short8 w3f[2], w4f[4], w5f[2];
#pragma unroll
  for (int t = 0; t < 2; t++) {
    const float* wp = w3 + (t * 16 + lr) * 32 + 8 * lq;
    short8 f;
#pragma unroll
    for (int j = 0; j < 8; j++) f[j] = (short)f2bf(wp[j]);
    w3f[t] = f;
  }
#pragma unroll
  for (int t = 0; t < 4; t++) {
    const float* wp = w4 + (t * 16 + lr) * 32 + 8 * lq;
    short8 f;
#pragma unroll
    for (int j = 0; j < 8; j++) f[j] = (short)f2bf(wp[j]);
    w4f[t] = f;
  }
#pragma unroll
  for (int t = 0; t < 2; t++) {
    const float* wp = w5 + (t * 16 + lr) * 32 + 8 * lq;
    short8 f;
#pragma unroll
    for (int j = 0; j < 8; j++) f[j] = (short)f2bf(wp[j]);
    w5f[t] = f;
  }

  float scv[8];  // SE scale for this lane's A-frag channels
#pragma unroll
  for (int j = 0; j < 8; j++) scv[j] = wf[OFF_SCALE + b * 32 + 8 * lq + j];

  float b3v[2], bev[2], n2wv[2], n2bv[2], b5v[2], gav[2], b4v[4];
#pragma unroll
  for (int t = 0; t < 2; t++) {
    b3v[t]  = wf[OFF_B3 + b * 32 + lr + 16 * t];
    bev[t]  = wf[OFF_BETA + lr + 16 * t];
    n2wv[t] = wf[OFF_N2W + lr + 16 * t];
    n2bv[t] = wf[OFF_N2B + lr + 16 * t];
    b5v[t]  = wf[OFF_B5 + b * 32 + lr + 16 * t];
    gav[t]  = wf[OFF_GAMMA + lr + 16 * t];
  }
#pragma unroll
  for (int t = 0; t < 4; t++) b4v[t] = wf[OFF_B4 + b * 64 + lr + 16 * t];

  const f32x4 zero = {0.f, 0.f, 0.f, 0.f};

#pragma unroll 1
  for (int it = 0; it < 4; it++) {
    const int P0 = blockIdx.x * 256 + wv * 64 + it * 16;

    // A-frag of SE-scaled x3: lane reads pix P0+lr at channels 8*lq+j
    short8 xaf;
#pragma unroll
    for (int j = 0; j < 8; j++) {
      float v = x3[ib + (((size_t)(8 * lq + j)) << 16) + P0 + lr] * scv[j];
      xaf[j] = (short)f2bf(v);
    }

    // conv3: 16 pix x 32 outs
    f32x4 d0 = __builtin_amdgcn_mfma_f32_16x16x32_bf16(xaf, w3f[0], zero, 0, 0, 0);
    f32x4 d1 = __builtin_amdgcn_mfma_f32_16x16x32_bf16(xaf, w3f[1], zero, 0, 0, 0);

    // y = inp + (conv3 + b3)*beta ; LN2 stats via 16-lane shfl_xor reduce
    float y[2][4], s[4], s2[4];
#pragma unroll
    for (int t = 0; t < 2; t++) {
      const f32x4 iv = *(const f32x4*)(inp + ib + (((size_t)(lr + 16 * t)) << 16) + P0 + 4 * lq);
      const f32x4 dd = t ? d1 : d0;
#pragma unroll
      for (int r = 0; r < 4; r++) y[t][r] = iv[r] + (dd[r] + b3v[t]) * bev[t];
    }
#pragma unroll
    for (int r = 0; r < 4; r++) {
      s[r]  = y[0][r] + y[1][r];
      s2[r] = y[0][r] * y[0][r] + y[1][r] * y[1][r];
    }
#pragma unroll
    for (int m = 1; m <= 8; m <<= 1) {
#pragma unroll
      for (int r = 0; r < 4; r++) {
        s[r]  += __shfl_xor(s[r], m, 64);
        s2[r] += __shfl_xor(s2[r], m, 64);
      }
    }
    float mu[4], rstd[4];
#pragma unroll
    for (int r = 0; r < 4; r++) {
      mu[r] = s[r] * (1.f / 32.f);
      const float var = fmaxf(s2[r] * (1.f / 32.f) - mu[r] * mu[r], 0.f);
      rstd[r] = rsqrtf(var + 1e-6f);
    }

    // z = LN2(y) -> bf16 -> LDS (D-layout write), read back as A-frag
#pragma unroll
    for (int t = 0; t < 2; t++) {
#pragma unroll
      for (int r = 0; r < 4; r++) {
        const float zz = (y[t][r] - mu[r]) * rstd[r] * n2wv[t] + n2bv[t];
        tbuf[wv][4 * lq + r][lr + 16 * t] = f2bf(zz);
      }
    }
    const short8 zf = *(const short8*)&tbuf[wv][lr][8 * lq];

    // conv4: 16 pix x 64 outs
    f32x4 e0 = __builtin_amdgcn_mfma_f32_16x16x32_bf16(zf, w4f[0], zero, 0, 0, 0);
    f32x4 e1 = __builtin_amdgcn_mfma_f32_16x16x32_bf16(zf, w4f[1], zero, 0, 0, 0);
    f32x4 e2 = __builtin_amdgcn_mfma_f32_16x16x32_bf16(zf, w4f[2], zero, 0, 0, 0);
    f32x4 e3 = __builtin_amdgcn_mfma_f32_16x16x32_bf16(zf, w4f[3], zero, 0, 0, 0);

    // SimpleGate: g[o] = (e[o]+b4[o]) * (e[o+32]+b4[o+32]) -> LDS -> A-frag
#pragma unroll
    for (int t = 0; t < 2; t++) {
      const f32x4 ea = t ? e1 : e0;
      const f32x4 eb = t ? e3 : e2;
#pragma unroll
      for (int r = 0; r < 4; r++) {
        const float gg = (ea[r] + b4v[t]) * (eb[r] + b4v[t + 2]);
        tbuf[wv][4 * lq + r][lr + 16 * t] = f2bf(gg);
      }
    }
    const short8 gf = *(const short8*)&tbuf[wv][lr][8 * lq];

    // conv5: 16 pix x 32 outs
    f32x4 f0 = __builtin_amdgcn_mfma_f32_16x16x32_bf16(gf, w5f[0], zero, 0, 0, 0);
    f32x4 f1 = __builtin_amdgcn_mfma_f32_16x16x32_bf16(gf, w5f[1], zero, 0, 0, 0);

    // out = y + (conv5 + b5)*gamma  (same D-layout as y -> float4 store)
#pragma unroll
    for (int t = 0; t < 2; t++) {
      const f32x4 ff = t ? f1 : f0;
      f32x4 ov;
#pragma unroll
      for (int r = 0; r < 4; r++) ov[r] = y[t][r] + (ff[r] + b5v[t]) * gav[t];
      *(f32x4*)(out + ib + (((size_t)(lr + 16 * t)) << 16) + P0 + 4 * lq) = ov;
    }
  }
}

extern "C" void kernel_launch(void* const* d_in, const int* in_sizes, int n_in,
                              void* d_out, int out_size, void* d_ws, size_t ws_size,
                              hipStream_t stream) {
  (void)in_sizes; (void)n_in; (void)out_size; (void)ws_size;
  const float* inp = (const float*)d_in[0];
  WPtrs p;
  p.w1 = (const float*)d_in[1];  p.b1 = (const float*)d_in[2];
  p.w2 = (const float*)d_in[3];  p.b2 = (const float*)d_in[4];
  p.w3 = (const float*)d_in[5];  p.b3 = (const float*)d_in[6];
  p.w4 = (const float*)d_in[7];  p.b4 = (const float*)d_in[8];
  p.w5 = (const float*)d_in[9];  p.b5 = (const float*)d_in[10];
  p.n1w = (const float*)d_in[11]; p.n1b = (const float*)d_in[12];
  p.n2w = (const float*)d_in[13]; p.n2b = (const float*)d_in[14];
  p.scaw = (const float*)d_in[15]; p.scab = (const float*)d_in[16];
  p.beta = (const float*)d_in[17]; p.gamma = (const float*)d_in[18];

  float* wf = (float*)d_ws;
  float* x3 = (float*)d_out;   // fp32 x3 lives in d_out (exact 128 MiB fit)
  float* out = (float*)d_out;

  k_pack<<<dim3(128), dim3(256), 0, stream>>>(p, wf);
  k_front<<<dim3(256, 16), dim3(256), 0, stream>>>(inp, wf, x3, wf + OFF_SSUM);
  k_sca<<<dim3(1), dim3(512), 0, stream>>>(wf);
  k_back<<<dim3(256, 16), dim3(256), 0, stream>>>(inp, x3, wf, out);
}

// Round 5
// 536.726 us; speedup vs baseline: 3.2241x; 2.9056x over previous
//
#include <hip/hip_runtime.h>

typedef unsigned short u16;
typedef unsigned int   u32;
typedef __attribute__((ext_vector_type(8))) short short8;  // 8 x bf16 MFMA frag
typedef __attribute__((ext_vector_type(4))) float f32x4;   // MFMA accumulator

#define DI static __device__ __forceinline__

// ---- problem constants ----
// B=16, C=32, DW=64, H=256, W=256, HW=65536. ALL inputs fp32, output fp32.
// x3 intermediate (gated tensor, 128 MiB fp32) lives in d_out: k_front writes
// it, k_back consumes and overwrites with the final output.
//
// [R4->R5: SE reduction de-atomic'd. R4 counters: k_front 1320 us with ALL
//  pipes idle (VALU 6.4%, HBM 3.2%, Mfma 0.2%) -> not instruction-bound.
//  Diagnosis: 524,288 device-scope atomicAdds onto 512 floats (32 cache
//  lines shared by 8 XCDs) serialize at the coherence point; waves linger
//  on vmcnt drain, blocking block launch. Evidence: k_back = same structure,
//  more HBM, no atomics -> ~150 us. Fix: per-block partial sums (LDS reduce,
//  one plain 32-float store/block) + two-stage reduce in k_sca. Zero atomics.]

// ---- workspace layout (float offsets) ----
static constexpr int OFF_SSUM = 0;        // (unused after R5; kept for layout)
static constexpr int OFF_SCALE = 512;     // 512
static constexpr int OFF_W1 = 1024;       // 16*64*32 = 32768
static constexpr int OFF_B1 = 33792;      // 1024
static constexpr int OFF_W2 = 34816;      // 16*64*9 = 9216
static constexpr int OFF_B2 = 44032;      // 1024
static constexpr int OFF_W3 = 45056;      // 16*32*32 = 16384
static constexpr int OFF_B3 = 61440;      // 512
static constexpr int OFF_W4 = 61952;      // 32768
static constexpr int OFF_B4 = 94720;      // 1024
static constexpr int OFF_W5 = 95744;      // 16384
static constexpr int OFF_B5 = 112128;     // 512
static constexpr int OFF_N1W = 112640;    // 32
static constexpr int OFF_N1B = 112672;    // 32
static constexpr int OFF_N2W = 112704;    // 32
static constexpr int OFF_N2B = 112736;    // 32
static constexpr int OFF_SCAW = 112768;   // 1024
static constexpr int OFF_SCAB = 113792;   // 32
static constexpr int OFF_BETA = 113824;   // 32
static constexpr int OFF_GAMMA = 113856;  // 32
static constexpr int OFF_PART = 113920;   // 4096 blocks * 32 ch = 131072 floats
// end = 245,  -> ~958 KiB total workspace

DI u16 f2bf(float f) {
  u32 x = __float_as_uint(f);
  u32 r = (x + 0x7fffu + ((x >> 16) & 1u)) >> 16;  // RNE
  return (u16)r;
}

struct WPtrs {
  const float *w1, *b1, *w2, *b2, *w3, *b3, *w4, *b4, *w5, *b5;
  const float *n1w, *n1b, *n2w, *n2b, *scaw, *scab, *beta, *gamma;
};

DI void cpy_seg(float* dst, const float* src, int n, int tid, int stride) {
  for (int i = tid; i < n; i += stride) dst[i] = src[i];
}

// ---- K0: gather all weights into contiguous fp32 ws ----
__global__ __launch_bounds__(256) void k_pack(WPtrs p, float* __restrict__ wf) {
  const int tid = blockIdx.x * 256 + threadIdx.x;
  const int stride = gridDim.x * 256;
  cpy_seg(wf + OFF_W1, p.w1, 32768, tid, stride);
  cpy_seg(wf + OFF_B1, p.b1, 1024, tid, stride);
  cpy_seg(wf + OFF_W2, p.w2, 9216, tid, stride);
  cpy_seg(wf + OFF_B2, p.b2, 1024, tid, stride);
  cpy_seg(wf + OFF_W3, p.w3, 16384, tid, stride);
  cpy_seg(wf + OFF_B3, p.b3, 512, tid, stride);
  cpy_seg(wf + OFF_W4, p.w4, 32768, tid, stride);
  cpy_seg(wf + OFF_B4, p.b4, 1024, tid, stride);
  cpy_seg(wf + OFF_W5, p.w5, 16384, tid, stride);
  cpy_seg(wf + OFF_B5, p.b5, 512, tid, stride);
  cpy_seg(wf + OFF_N1W, p.n1w, 32, tid, stride);
  cpy_seg(wf + OFF_N1B, p.n1b, 32, tid, stride);
  cpy_seg(wf + OFF_N2W, p.n2w, 32, tid, stride);
  cpy_seg(wf + OFF_N2B, p.n2b, 32, tid, stride);
  cpy_seg(wf + OFF_SCAW, p.scaw, 1024, tid, stride);
  cpy_seg(wf + OFF_SCAB, p.scab, 32, tid, stride);
  cpy_seg(wf + OFF_BETA, p.beta, 32, tid, stride);
  cpy_seg(wf + OFF_GAMMA, p.gamma, 32, tid, stride);
}

// ---- K1: (A) LN1 -> bf16 LDS tile; (B) conv1x1(32->64) via MFMA; (C) dwconv3x3
// + SimpleGate -> x3 + per-block SE partial sums (NO atomics).
__global__ __launch_bounds__(256) void k_front(const float* __restrict__ inp,
                                               const float* __restrict__ wf,
                                               float* __restrict__ x3,
                                               float* __restrict__ part) {
  const int tid = threadIdx.x;
  const int b = blockIdx.y;
  const int tile = blockIdx.x;        // 8 tiles in x, 32 in y
  const int tx = tile & 7, ty = tile >> 3;
  const int gx0 = tx * 32 - 1, gy0 = ty * 8 - 1;

  __shared__ u16 xln[352][40];   // LN'd input, bf16, pad-40 rows (28160 B)
  __shared__ u32 x1p[32][340];   // conv1 out, packed bf16 pairs  (43520 B)
  __shared__ float psum[4][32];  // per-wave SE partials           (512 B)

  const float* w1 = wf + OFF_W1 + b * 2048;
  const float* b1 = wf + OFF_B1 + b * 64;
  const float* n1w = wf + OFF_N1W;
  const float* n1b = wf + OFF_N1B;

  // ---- stage A: LN per halo pixel -> bf16 -> xln ----
#pragma unroll 1
  for (int idx = tid; idx < 352; idx += 256) {
    const int py = idx / 34;
    const int px = idx - py * 34;
    const int gy = gy0 + py, gx = gx0 + px;
    u32 pk[16];
    if (idx >= 340 || (u32)gy >= 256u || (u32)gx >= 256u) {
#pragma unroll
      for (int j = 0; j < 16; j++) pk[j] = 0u;
    } else {
      const float* src = inp + (((size_t)(b * 32)) << 16) + (gy << 8) + gx;
      float x[32];
      float s = 0.f, s2 = 0.f;
#pragma unroll
      for (int c = 0; c < 32; c++) {
        float v = src[(size_t)c << 16];
        x[c] = v; s += v; s2 += v * v;
      }
      const float mu = s * (1.f / 32.f);
      const float var = fmaxf(s2 * (1.f / 32.f) - mu * mu, 0.f);
      const float rstd = rsqrtf(var + 1e-6f);
#pragma unroll
      for (int j = 0; j < 16; j++) {
        const float lo = (x[2 * j] - mu) * rstd * n1w[2 * j] + n1b[2 * j];
        const float hi = (x[2 * j + 1] - mu) * rstd * n1w[2 * j + 1] + n1b[2 * j + 1];
        pk[j] = (u32)f2bf(lo) | ((u32)f2bf(hi) << 16);
      }
    }
    u32* row = (u32*)&xln[idx][0];  // 80 B rows -> always 16B aligned
#pragma unroll
    for (int q = 0; q < 4; q++)
      *(uint4*)(row + 4 * q) = make_uint4(pk[4 * q], pk[4 * q + 1], pk[4 * q + 2], pk[4 * q + 3]);
  }

  // ---- W1 B-frags + biases (global loads, independent of stage A) ----
  const int lane = tid & 63;
  const int wv = tid >> 6;
  const int lr = lane & 15;
  const int lq = lane >> 4;

  short8 w1f[4];
#pragma unroll
  for (int t = 0; t < 4; t++) {
    const float* wp = w1 + (t * 16 + lr) * 32 + 8 * lq;
    short8 f;
#pragma unroll
    for (int j = 0; j < 8; j++) f[j] = (short)f2bf(wp[j]);
    w1f[t] = f;
  }
  float b1v[4];
#pragma unroll
  for (int t = 0; t < 4; t++) b1v[t] = b1[t * 16 + lr];

  __syncthreads();

  // ---- stage B: conv1 via MFMA, 22 groups of 16 pixels ----
  const f32x4 zero = {0.f, 0.f, 0.f, 0.f};
#pragma unroll 1
  for (int g = wv; g < 22; g += 4) {
    const short8 af = *(const short8*)&xln[16 * g + lr][8 * lq];
    f32x4 d0 = __builtin_amdgcn_mfma_f32_16x16x32_bf16(af, w1f[0], zero, 0, 0, 0);
    f32x4 d1 = __builtin_amdgcn_mfma_f32_16x16x32_bf16(af, w1f[1], zero, 0, 0, 0);
    f32x4 d2 = __builtin_amdgcn_mfma_f32_16x16x32_bf16(af, w1f[2], zero, 0, 0, 0);
    f32x4 d3 = __builtin_amdgcn_mfma_f32_16x16x32_bf16(af, w1f[3], zero, 0, 0, 0);
#pragma unroll
    for (int r = 0; r < 4; r++) {
      const int pix = 16 * g + 4 * lq + r;
      if (pix < 340) {
        const int py = pix / 34;
        const int px = pix - 34 * py;
        const int gy = gy0 + py, gx = gx0 + px;
        u32 v0 = 0u, v1 = 0u;
        if (((u32)gy < 256u) & ((u32)gx < 256u)) {
          v0 = (u32)f2bf(d0[r] + b1v[0]) | ((u32)f2bf(d2[r] + b1v[2]) << 16);
          v1 = (u32)f2bf(d1[r] + b1v[1]) | ((u32)f2bf(d3[r] + b1v[3]) << 16);
        }
        x1p[lr][pix] = v0;
        x1p[lr + 16][pix] = v1;
      }
    }
  }
  __syncthreads();

  // ---- stage C: dwconv3x3 + SimpleGate -> x3; per-wave SE partials to LDS ----
  const int px = tid & 31, py = tid >> 5;  // 32x8 interior
  const int p = (py + 1) * 34 + (px + 1);
  const int gpix = ((ty * 8 + py) << 8) + (tx * 32 + px);
  const float* w2 = wf + OFF_W2 + b * 576;
  const float* b2 = wf + OFF_B2 + b * 64;
  float* ob = x3 + (((size_t)(b * 32)) << 16) + gpix;

#pragma unroll 2
  for (int c = 0; c < 32; c++) {
    float a1 = b2[c], a2 = b2[c + 32];
    const int offs[9] = {-35, -34, -33, -1, 0, 1, 33, 34, 35};
#pragma unroll
    for (int k = 0; k < 9; k++) {
      const u32 u = x1p[c][p + offs[k]];
      const float lo = __uint_as_float(u << 16);
      const float hi = __uint_as_float(u & 0xffff0000u);
      a1 += lo * w2[c * 9 + k];
      a2 += hi * w2[(c + 32) * 9 + k];
    }
    const float v = a1 * a2;  // SimpleGate
    ob[(size_t)c << 16] = v;
    float r = v;
#pragma unroll
    for (int off = 32; off > 0; off >>= 1) r += __shfl_xor(r, off, 64);
    if ((tid & 63) == 0) psum[wv][c] = r;
  }
  __syncthreads();

  // one plain coalesced 32-float store per block (replaces 128 atomics)
  if (tid < 32) {
    const float t4 = psum[0][tid] + psum[1][tid] + psum[2][tid] + psum[3][tid];
    part[(((b << 8) + tile) << 5) + tid] = t4;
  }
}

// ---- K2: SE head: reduce 256 per-tile partials -> mean -> 32x32 matmul ----
__global__ __launch_bounds__(256) void k_sca(float* __restrict__ wf) {
  const int b = blockIdx.x;
  const int tid = threadIdx.x;
  const int q = tid >> 5, c = tid & 31;
  __shared__ float l[8][32];
  __shared__ float sv[32];
  const float* part = wf + OFF_PART + b * 8192;  // 256 tiles * 32 ch
  float a = 0.f;
#pragma unroll 4
  for (int t = q; t < 256; t += 8) a += part[t * 32 + c];
  l[q][c] = a;
  __syncthreads();
  if (tid < 32) {
    float s = 0.f;
#pragma unroll
    for (int qq = 0; qq < 8; qq++) s += l[qq][tid];
    sv[tid] = s * (1.f / 65536.f);
  }
  __syncthreads();
  if (tid < 32) {
    const float* sw = wf + OFF_SCAW;
    float acc = wf[OFF_SCAB + tid];
#pragma unroll
    for (int cc = 0; cc < 32; cc++) acc += sv[cc] * sw[tid * 32 + cc];
    wf[OFF_SCALE + b * 32 + tid] = acc;
  }
}

// ---- K3 (MFMA): scale*x3 -> conv3 -> beta-res -> LN2 -> conv4 -> SG -> conv5
//                 -> gamma-res.  [unchanged from R2/R3 verified version]
__global__ __launch_bounds__(256) void k_back(const float* __restrict__ inp,
                                              const float* x3,
                                              const float* __restrict__ wf,
                                              float* out) {
  const int tid = threadIdx.x;
  const int b = blockIdx.y;
  const int wv = tid >> 6;       // 4 waves/block
  const int lane = tid & 63;
  const int lr = lane & 15;
  const int lq = lane >> 4;

  __shared__ u16 tbuf[4][16][40];  // per-wave transpose tile (5120 B)

  const size_t ib = ((size_t)(b * 32)) << 16;
  const float* w3 = wf + OFF_W3 + b * 1024;
  const float* w4 = wf + OFF_W4 + b * 2048;
  const float* w5 = wf + OFF_W5 + b * 1024;

  // B-frags: lane reads W[o = t*16+lr][8*lq .. 8*lq+7], fp32 -> bf16 RNE
  short8 w3f[2], w4f[4], w5f[2];
#pragma unroll
  for (int t = 0; t < 2; t++) {
    const float* wp = w3 + (t * 16 + lr) * 32 + 8 * lq;
    short8 f;
#pragma unroll
    for (int j = 0; j < 8; j++) f[j] = (short)f2bf(wp[j]);
    w3f[t] = f;
  }
#pragma unroll
  for (int t = 0; t < 4; t++) {
    const float* wp = w4 + (t * 16 + lr) * 32 + 8 * lq;
    short8 f;
#pragma unroll
    for (int j = 0; j < 8; j++) f[j] = (short)f2bf(wp[j]);
    w4f[t] = f;
  }
#pragma unroll
  for (int t = 0; t < 2; t++) {
    const float* wp = w5 + (t * 16 + lr) * 32 + 8 * lq;
    short8 f;
#pragma unroll
    for (int j = 0; j < 8; j++) f[j] = (short)f2bf(wp[j]);
    w5f[t] = f;
  }

  float scv[8];  // SE scale for this lane's A-frag channels
#pragma unroll
  for (int j = 0; j < 8; j++) scv[j] = wf[OFF_SCALE + b * 32 + 8 * lq + j];

  float b3v[2], bev[2], n2wv[2], n2bv[2], b5v[2], gav[2], b4v[4];
#pragma unroll
  for (int t = 0; t < 2; t++) {
    b3v[t]  = wf[OFF_B3 + b * 32 + lr + 16 * t];
    bev[t]  = wf[OFF_BETA + lr + 16 * t];
    n2wv[t] = wf[OFF_N2W + lr + 16 * t];
    n2bv[t] = wf[OFF_N2B + lr + 16 * t];
    b5v[t]  = wf[OFF_B5 + b * 32 + lr + 16 * t];
    gav[t]  = wf[OFF_GAMMA + lr + 16 * t];
  }
#pragma unroll
  for (int t = 0; t < 4; t++) b4v[t] = wf[OFF_B4 + b * 64 + lr + 16 * t];

  const f32x4 zero = {0.f, 0.f, 0.f, 0.f};

#pragma unroll 1
  for (int it = 0; it < 4; it++) {
    const int P0 = blockIdx.x * 256 + wv * 64 + it * 16;

    // A-frag of SE-scaled x3: lane reads pix P0+lr at channels 8*lq+j
    short8 xaf;
#pragma unroll
    for (int j = 0; j < 8; j++) {
      float v = x3[ib + (((size_t)(8 * lq + j)) << 16) + P0 + lr] * scv[j];
      xaf[j] = (short)f2bf(v);
    }

    // conv3: 16 pix x 32 outs
    f32x4 d0 = __builtin_amdgcn_mfma_f32_16x16x32_bf16(xaf, w3f[0], zero, 0, 0, 0);
    f32x4 d1 = __builtin_amdgcn_mfma_f32_16x16x32_bf16(xaf, w3f[1], zero, 0, 0, 0);

    // y = inp + (conv3 + b3)*beta ; LN2 stats via 16-lane shfl_xor reduce
    float y[2][4], s[4], s2[4];
#pragma unroll
    for (int t = 0; t < 2; t++) {
      const f32x4 iv = *(const f32x4*)(inp + ib + (((size_t)(lr + 16 * t)) << 16) + P0 + 4 * lq);
      const f32x4 dd = t ? d1 : d0;
#pragma unroll
      for (int r = 0; r < 4; r++) y[t][r] = iv[r] + (dd[r] + b3v[t]) * bev[t];
    }
#pragma unroll
    for (int r = 0; r < 4; r++) {
      s[r]  = y[0][r] + y[1][r];
      s2[r] = y[0][r] * y[0][r] + y[1][r] * y[1][r];
    }
#pragma unroll
    for (int m = 1; m <= 8; m <<= 1) {
#pragma unroll
      for (int r = 0; r < 4; r++) {
        s[r]  += __shfl_xor(s[r], m, 64);
        s2[r] += __shfl_xor(s2[r], m, 64);
      }
    }
    float mu[4], rstd[4];
#pragma unroll
    for (int r = 0; r < 4; r++) {
      mu[r] = s[r] * (1.f / 32.f);
      const float var = fmaxf(s2[r] * (1.f / 32.f) - mu[r] * mu[r], 0.f);
      rstd[r] = rsqrtf(var + 1e-6f);
    }

    // z = LN2(y) -> bf16 -> LDS (D-layout write), read back as A-frag
#pragma unroll
    for (int t = 0; t < 2; t++) {
#pragma unroll
      for (int r = 0; r < 4; r++) {
        const float zz = (y[t][r] - mu[r]) * rstd[r] * n2wv[t] + n2bv[t];
        tbuf[wv][4 * lq + r][lr + 16 * t] = f2bf(zz);
      }
    }
    const short8 zf = *(const short8*)&tbuf[wv][lr][8 * lq];

    // conv4: 16 pix x 64 outs
    f32x4 e0 = __builtin_amdgcn_mfma_f32_16x16x32_bf16(zf, w4f[0], zero, 0, 0, 0);
    f32x4 e1 = __builtin_amdgcn_mfma_f32_16x16x32_bf16(zf, w4f[1], zero, 0, 0, 0);
    f32x4 e2 = __builtin_amdgcn_mfma_f32_16x16x32_bf16(zf, w4f[2], zero, 0, 0, 0);
    f32x4 e3 = __builtin_amdgcn_mfma_f32_16x16x32_bf16(zf, w4f[3], zero, 0, 0, 0);

    // SimpleGate: g[o] = (e[o]+b4[o]) * (e[o+32]+b4[o+32]) -> LDS -> A-frag
#pragma unroll
    for (int t = 0; t < 2; t++) {
      const f32x4 ea = t ? e1 : e0;
      const f32x4 eb = t ? e3 : e2;
#pragma unroll
      for (int r = 0; r < 4; r++) {
        const float gg = (ea[r] + b4v[t]) * (eb[r] + b4v[t + 2]);
        tbuf[wv][4 * lq + r][lr + 16 * t] = f2bf(gg);
      }
    }
    const short8 gf = *(const short8*)&tbuf[wv][lr][8 * lq];

    // conv5: 16 pix x 32 outs
    f32x4 f0 = __builtin_amdgcn_mfma_f32_16x16x32_bf16(gf, w5f[0], zero, 0, 0, 0);
    f32x4 f1 = __builtin_amdgcn_mfma_f32_16x16x32_bf16(gf, w5f[1], zero, 0, 0, 0);

    // out = y + (conv5 + b5)*gamma  (same D-layout as y -> float4 store)
#pragma unroll
    for (int t = 0; t < 2; t++) {
      const f32x4 ff = t ? f1 : f0;
      f32x4 ov;
#pragma unroll
      for (int r = 0; r < 4; r++) ov[r] = y[t][r] + (ff[r] + b5v[t]) * gav[t];
      *(f32x4*)(out + ib + (((size_t)(lr + 16 * t)) << 16) + P0 + 4 * lq) = ov;
    }
  }
}

extern "C" void kernel_launch(void* const* d_in, const int* in_sizes, int n_in,
                              void* d_out, int out_size, void* d_ws, size_t ws_size,
                              hipStream_t stream) {
  (void)in_sizes; (void)n_in; (void)out_size; (void)ws_size;
  const float* inp = (const float*)d_in[0];
  WPtrs p;
  p.w1 = (const float*)d_in[1];  p.b1 = (const float*)d_in[2];
  p.w2 = (const float*)d_in[3];  p.b2 = (const float*)d_in[4];
  p.w3 = (const float*)d_in[5];  p.b3 = (const float*)d_in[6];
  p.w4 = (const float*)d_in[7];  p.b4 = (const float*)d_in[8];
  p.w5 = (const float*)d_in[9];  p.b5 = (const float*)d_in[10];
  p.n1w = (const float*)d_in[11]; p.n1b = (const float*)d_in[12];
  p.n2w = (const float*)d_in[13]; p.n2b = (const float*)d_in[14];
  p.scaw = (const float*)d_in[15]; p.scab = (const float*)d_in[16];
  p.beta = (const float*)d_in[17]; p.gamma = (const float*)d_in[18];

  float* wf = (float*)d_ws;
  float* x3 = (float*)d_out;   // fp32 x3 lives in d_out (exact 128 MiB fit)
  float* out = (float*)d_out;

  k_pack<<<dim3(128), dim3(256), 0, stream>>>(p, wf);
  k_front<<<dim3(256, 16), dim3(256), 0, stream>>>(inp, wf, x3, wf + OFF_PART);
  k_sca<<<dim3(16), dim3(256), 0, stream>>>(wf);
  k_back<<<dim3(256, 16), dim3(256), 0, stream>>>(inp, x3, wf, out);
}

// Round 6
// 514.443 us; speedup vs baseline: 3.3638x; 1.0433x over previous
//
#include <hip/hip_runtime.h>

typedef unsigned short u16;
typedef unsigned int   u32;
typedef __attribute__((ext_vector_type(8))) short short8;  // 8 x bf16 MFMA frag
typedef __attribute__((ext_vector_type(4))) float f32x4;   // MFMA accumulator

#define DI static __device__ __forceinline__

// ---- problem constants ----
// B=16, C=32, DW=64, H=256, W=256, HW=65536. ALL inputs fp32, output fp32.
// x3 intermediate (gated tensor, 128 MiB fp32) lives in d_out: k_front writes
// it, k_back consumes and overwrites with the final output.
//
// [R5->R6: k_front LDS diet for occupancy. R5 counters: k_front 245 us,
//  VALUBusy 33%, Occ 22.9% == the 2-blocks/CU LDS ceiling (72.2 KiB/block).
//  Latency-bound at 2 waves/SIMD. Fix: split conv1 output channel-wise into
//  two B/C passes over a half-size x1h[16][341] buffer (pad 341: gcd(21,32)=1
//  breaks the stride-340 8-way write conflicts). LDS 72.2 -> 49.3 KiB ->
//  3 blocks/CU. Stage-C unroll 4. k_back UNTOUCHED: no counters for it yet;
//  it becomes the top dispatch next round and gets an evidence-based fix.]

// ---- workspace layout (float offsets) ----
static constexpr int OFF_SSUM = 0;        // (unused; kept for layout)
static constexpr int OFF_SCALE = 512;     // 512
static constexpr int OFF_W1 = 1024;       // 16*64*32 = 32768
static constexpr int OFF_B1 = 33792;      // 1024
static constexpr int OFF_W2 = 34816;      // 16*64*9 = 9216
static constexpr int OFF_B2 = 44032;      // 1024
static constexpr int OFF_W3 = 45056;      // 16*32*32 = 16384
static constexpr int OFF_B3 = 61440;      // 512
static constexpr int OFF_W4 = 61952;      // 32768
static constexpr int OFF_B4 = 94720;      // 1024
static constexpr int OFF_W5 = 95744;      // 16384
static constexpr int OFF_B5 = 112128;     // 512
static constexpr int OFF_N1W = 112640;    // 32
static constexpr int OFF_N1B = 112672;    // 32
static constexpr int OFF_N2W = 112704;    // 32
static constexpr int OFF_N2B = 112736;    // 32
static constexpr int OFF_SCAW = 112768;   // 1024
static constexpr int OFF_SCAB = 113792;   // 32
static constexpr int OFF_BETA = 113824;   // 32
static constexpr int OFF_GAMMA = 113856;  // 32
static constexpr int OFF_PART = 113920;   // 4096 blocks * 32 ch = 131072 floats

DI u16 f2bf(float f) {
  u32 x = __float_as_uint(f);
  u32 r = (x + 0x7fffu + ((x >> 16) & 1u)) >> 16;  // RNE
  return (u16)r;
}

struct WPtrs {
  const float *w1, *b1, *w2, *b2, *w3, *b3, *w4, *b4, *w5, *b5;
  const float *n1w, *n1b, *n2w, *n2b, *scaw, *scab, *beta, *gamma;
};

DI void cpy_seg(float* dst, const float* src, int n, int tid, int stride) {
  for (int i = tid; i < n; i += stride) dst[i] = src[i];
}

// ---- K0: gather all weights into contiguous fp32 ws ----
__global__ __launch_bounds__(256) void k_pack(WPtrs p, float* __restrict__ wf) {
  const int tid = blockIdx.x * 256 + threadIdx.x;
  const int stride = gridDim.x * 256;
  cpy_seg(wf + OFF_W1, p.w1, 32768, tid, stride);
  cpy_seg(wf + OFF_B1, p.b1, 1024, tid, stride);
  cpy_seg(wf + OFF_W2, p.w2, 9216, tid, stride);
  cpy_seg(wf + OFF_B2, p.b2, 1024, tid, stride);
  cpy_seg(wf + OFF_W3, p.w3, 16384, tid, stride);
  cpy_seg(wf + OFF_B3, p.b3, 512, tid, stride);
  cpy_seg(wf + OFF_W4, p.w4, 32768, tid, stride);
  cpy_seg(wf + OFF_B4, p.b4, 1024, tid, stride);
  cpy_seg(wf + OFF_W5, p.w5, 16384, tid, stride);
  cpy_seg(wf + OFF_B5, p.b5, 512, tid, stride);
  cpy_seg(wf + OFF_N1W, p.n1w, 32, tid, stride);
  cpy_seg(wf + OFF_N1B, p.n1b, 32, tid, stride);
  cpy_seg(wf + OFF_N2W, p.n2w, 32, tid, stride);
  cpy_seg(wf + OFF_N2B, p.n2b, 32, tid, stride);
  cpy_seg(wf + OFF_SCAW, p.scaw, 1024, tid, stride);
  cpy_seg(wf + OFF_SCAB, p.scab, 32, tid, stride);
  cpy_seg(wf + OFF_BETA, p.beta, 32, tid, stride);
  cpy_seg(wf + OFF_GAMMA, p.gamma, 32, tid, stride);
}

// ---- K1: (A) LN1 -> bf16 LDS tile; then TWO passes of {(B) conv1x1 via MFMA
// for 16 channel-pairs; (C) dwconv3x3 + SimpleGate for those 16 channels}.
// Channel pairs: pass ph covers (ph*16+cc, ph*16+cc+32), cc in [0,16).
// Per-block SE partials, no atomics.
__global__ __launch_bounds__(256) void k_front(const float* __restrict__ inp,
                                               const float* __restrict__ wf,
                                               float* __restrict__ x3,
                                               float* __restrict__ part) {
  const int tid = threadIdx.x;
  const int b = blockIdx.y;
  const int tile = blockIdx.x;        // 8 tiles in x, 32 in y
  const int tx = tile & 7, ty = tile >> 3;
  const int gx0 = tx * 32 - 1, gy0 = ty * 8 - 1;

  __shared__ u16 xln[352][40];   // LN'd input, bf16, pad-40 rows (28160 B)
  __shared__ u32 x1h[16][341];   // conv1 out half, packed pairs  (21824 B)
  __shared__ float psum[4][32];  // per-wave SE partials           (512 B)
  // total 50496 B -> 3 blocks/CU (vs 72192 B -> 2 blocks/CU in R5)

  const float* w1 = wf + OFF_W1 + b * 2048;
  const float* b1 = wf + OFF_B1 + b * 64;
  const float* n1w = wf + OFF_N1W;
  const float* n1b = wf + OFF_N1B;

  // ---- stage A: LN per halo pixel -> bf16 -> xln ----
#pragma unroll 1
  for (int idx = tid; idx < 352; idx += 256) {
    const int py = idx / 34;
    const int px = idx - py * 34;
    const int gy = gy0 + py, gx = gx0 + px;
    u32 pk[16];
    if (idx >= 340 || (u32)gy >= 256u || (u32)gx >= 256u) {
#pragma unroll
      for (int j = 0; j < 16; j++) pk[j] = 0u;
    } else {
      const float* src = inp + (((size_t)(b * 32)) << 16) + (gy << 8) + gx;
      float x[32];
      float s = 0.f, s2 = 0.f;
#pragma unroll
      for (int c = 0; c < 32; c++) {
        float v = src[(size_t)c << 16];
        x[c] = v; s += v; s2 += v * v;
      }
      const float mu = s * (1.f / 32.f);
      const float var = fmaxf(s2 * (1.f / 32.f) - mu * mu, 0.f);
      const float rstd = rsqrtf(var + 1e-6f);
#pragma unroll
      for (int j = 0; j < 16; j++) {
        const float lo = (x[2 * j] - mu) * rstd * n1w[2 * j] + n1b[2 * j];
        const float hi = (x[2 * j + 1] - mu) * rstd * n1w[2 * j + 1] + n1b[2 * j + 1];
        pk[j] = (u32)f2bf(lo) | ((u32)f2bf(hi) << 16);
      }
    }
    u32* row = (u32*)&xln[idx][0];  // 80 B rows -> always 16B aligned
#pragma unroll
    for (int q = 0; q < 4; q++)
      *(uint4*)(row + 4 * q) = make_uint4(pk[4 * q], pk[4 * q + 1], pk[4 * q + 2], pk[4 * q + 3]);
  }

  // ---- W1 B-frags + biases (global loads, independent of stage A) ----
  const int lane = tid & 63;
  const int wv = tid >> 6;
  const int lr = lane & 15;
  const int lq = lane >> 4;

  short8 w1f[4];
#pragma unroll
  for (int t = 0; t < 4; t++) {
    const float* wp = w1 + (t * 16 + lr) * 32 + 8 * lq;
    short8 f;
#pragma unroll
    for (int j = 0; j < 8; j++) f[j] = (short)f2bf(wp[j]);
    w1f[t] = f;
  }
  float b1v[4];
#pragma unroll
  for (int t = 0; t < 4; t++) b1v[t] = b1[t * 16 + lr];

  // stage-C geometry (computed once)
  const int cpx = tid & 31, cpy = tid >> 5;  // 32x8 interior
  const int p = (cpy + 1) * 34 + (cpx + 1);
  const int gpix = ((ty * 8 + cpy) << 8) + (tx * 32 + cpx);
  const float* w2 = wf + OFF_W2 + b * 576;
  const float* b2 = wf + OFF_B2 + b * 64;
  float* ob = x3 + (((size_t)(b * 32)) << 16) + gpix;

  __syncthreads();

  const f32x4 zero = {0.f, 0.f, 0.f, 0.f};

#pragma unroll 1
  for (int ph = 0; ph < 2; ph++) {
    // ---- stage B (pass ph): conv1 channels {ph*16+lr, ph*16+lr+32} ----
#pragma unroll 1
    for (int g = wv; g < 22; g += 4) {
      const short8 af = *(const short8*)&xln[16 * g + lr][8 * lq];
      f32x4 dA = __builtin_amdgcn_mfma_f32_16x16x32_bf16(af, w1f[ph], zero, 0, 0, 0);
      f32x4 dB = __builtin_amdgcn_mfma_f32_16x16x32_bf16(af, w1f[ph + 2], zero, 0, 0, 0);
#pragma unroll
      for (int r = 0; r < 4; r++) {
        const int pix = 16 * g + 4 * lq + r;
        if (pix < 340) {
          const int py = pix / 34;
          const int px = pix - 34 * py;
          const int gy = gy0 + py, gx = gx0 + px;
          u32 v = 0u;
          if (((u32)gy < 256u) & ((u32)gx < 256u))
            v = (u32)f2bf(dA[r] + b1v[ph]) | ((u32)f2bf(dB[r] + b1v[ph + 2]) << 16);
          x1h[lr][pix] = v;
        }
      }
    }
    __syncthreads();

    // ---- stage C (pass ph): dwconv3x3 + gate for channels ph*16 .. ph*16+15 ----
#pragma unroll 4
    for (int cc = 0; cc < 16; cc++) {
      const int c = ph * 16 + cc;
      float a1 = b2[c], a2 = b2[c + 32];
      const int offs[9] = {-35, -34, -33, -1, 0, 1, 33, 34, 35};
#pragma unroll
      for (int k = 0; k < 9; k++) {
        const u32 u = x1h[cc][p + offs[k]];
        const float lo = __uint_as_float(u << 16);
        const float hi = __uint_as_float(u & 0xffff0000u);
        a1 += lo * w2[c * 9 + k];
        a2 += hi * w2[(c + 32) * 9 + k];
      }
      const float v = a1 * a2;  // SimpleGate
      ob[(size_t)c << 16] = v;
      float r = v;
#pragma unroll
      for (int off = 32; off > 0; off >>= 1) r += __shfl_xor(r, off, 64);
      if ((tid & 63) == 0) psum[wv][c] = r;
    }
    __syncthreads();  // protects x1h reuse (ph=0) / psum completeness (ph=1)
  }

  // one plain coalesced 32-float store per block
  if (tid < 32) {
    const float t4 = psum[0][tid] + psum[1][tid] + psum[2][tid] + psum[3][tid];
    part[(((b << 8) + tile) << 5) + tid] = t4;
  }
}

// ---- K2: SE head: reduce 256 per-tile partials -> mean -> 32x32 matmul ----
__global__ __launch_bounds__(256) void k_sca(float* __restrict__ wf) {
  const int b = blockIdx.x;
  const int tid = threadIdx.x;
  const int q = tid >> 5, c = tid & 31;
  __shared__ float l[8][32];
  __shared__ float sv[32];
  const float* part = wf + OFF_PART + b * 8192;  // 256 tiles * 32 ch
  float a = 0.f;
#pragma unroll 4
  for (int t = q; t < 256; t += 8) a += part[t * 32 + c];
  l[q][c] = a;
  __syncthreads();
  if (tid < 32) {
    float s = 0.f;
#pragma unroll
    for (int qq = 0; qq < 8; qq++) s += l[qq][tid];
    sv[tid] = s * (1.f / 65536.f);
  }
  __syncthreads();
  if (tid < 32) {
    const float* sw = wf + OFF_SCAW;
    float acc = wf[OFF_SCAB + tid];
#pragma unroll
    for (int cc = 0; cc < 32; cc++) acc += sv[cc] * sw[tid * 32 + cc];
    wf[OFF_SCALE + b * 32 + tid] = acc;
  }
}

// ---- K3 (MFMA): scale*x3 -> conv3 -> beta-res -> LN2 -> conv4 -> SG -> conv5
//                 -> gamma-res.  [unchanged from R2/R3 verified version]
__global__ __launch_bounds__(256) void k_back(const float* __restrict__ inp,
                                              const float* x3,
                                              const float* __restrict__ wf,
                                              float* out) {
  const int tid = threadIdx.x;
  const int b = blockIdx.y;
  const int wv = tid >> 6;       // 4 waves/block
  const int lane = tid & 63;
  const int lr = lane & 15;
  const int lq = lane >> 4;

  __shared__ u16 tbuf[4][16][40];  // per-wave transpose tile (5120 B)

  const size_t ib = ((size_t)(b * 32)) << 16;
  const float* w3 = wf + OFF_W3 + b * 1024;
  const float* w4 = wf + OFF_W4 + b * 2048;
  const float* w5 = wf + OFF_W5 + b * 1024;

  // B-frags: lane reads W[o = t*16+lr][8*lq .. 8*lq+7], fp32 -> bf16 RNE
  short8 w3f[2], w4f[4], w5f[2];
#pragma unroll
  for (int t = 0; t < 2; t++) {
    const float* wp = w3 + (t * 16 + lr) * 32 + 8 * lq;
    short8 f;
#pragma unroll
    for (int j = 0; j < 8; j++) f[j] = (short)f2bf(wp[j]);
    w3f[t] = f;
  }
#pragma unroll
  for (int t = 0; t < 4; t++) {
    const float* wp = w4 + (t * 16 + lr) * 32 + 8 * lq;
    short8 f;
#pragma unroll
    for (int j = 0; j < 8; j++) f[j] = (short)f2bf(wp[j]);
    w4f[t] = f;
  }
#pragma unroll
  for (int t = 0; t < 2; t++) {
    const float* wp = w5 + (t * 16 + lr) * 32 + 8 * lq;
    short8 f;
#pragma unroll
    for (int j = 0; j < 8; j++) f[j] = (short)f2bf(wp[j]);
    w5f[t] = f;
  }

  float scv[8];  // SE scale for this lane's A-frag channels
#pragma unroll
  for (int j = 0; j < 8; j++) scv[j] = wf[OFF_SCALE + b * 32 + 8 * lq + j];

  float b3v[2], bev[2], n2wv[2], n2bv[2], b5v[2], gav[2], b4v[4];
#pragma unroll
  for (int t = 0; t < 2; t++) {
    b3v[t]  = wf[OFF_B3 + b * 32 + lr + 16 * t];
    bev[t]  = wf[OFF_BETA + lr + 16 * t];
    n2wv[t] = wf[OFF_N2W + lr + 16 * t];
    n2bv[t] = wf[OFF_N2B + lr + 16 * t];
    b5v[t]  = wf[OFF_B5 + b * 32 + lr + 16 * t];
    gav[t]  = wf[OFF_GAMMA + lr + 16 * t];
  }
#pragma unroll
  for (int t = 0; t < 4; t++) b4v[t] = wf[OFF_B4 + b * 64 + lr + 16 * t];

  const f32x4 zero = {0.f, 0.f, 0.f, 0.f};

#pragma unroll 1
  for (int it = 0; it < 4; it++) {
    const int P0 = blockIdx.x * 256 + wv * 64 + it * 16;

    // A-frag of SE-scaled x3: lane reads pix P0+lr at channels 8*lq+j
    short8 xaf;
#pragma unroll
    for (int j = 0; j < 8; j++) {
      float v = x3[ib + (((size_t)(8 * lq + j)) << 16) + P0 + lr] * scv[j];
      xaf[j] = (short)f2bf(v);
    }

    // conv3: 16 pix x 32 outs
    f32x4 d0 = __builtin_amdgcn_mfma_f32_16x16x32_bf16(xaf, w3f[0], zero, 0, 0, 0);
    f32x4 d1 = __builtin_amdgcn_mfma_f32_16x16x32_bf16(xaf, w3f[1], zero, 0, 0, 0);

    // y = inp + (conv3 + b3)*beta ; LN2 stats via 16-lane shfl_xor reduce
    float y[2][4], s[4], s2[4];
#pragma unroll
    for (int t = 0; t < 2; t++) {
      const f32x4 iv = *(const f32x4*)(inp + ib + (((size_t)(lr + 16 * t)) << 16) + P0 + 4 * lq);
      const f32x4 dd = t ? d1 : d0;
#pragma unroll
      for (int r = 0; r < 4; r++) y[t][r] = iv[r] + (dd[r] + b3v[t]) * bev[t];
    }
#pragma unroll
    for (int r = 0; r < 4; r++) {
      s[r]  = y[0][r] + y[1][r];
      s2[r] = y[0][r] * y[0][r] + y[1][r] * y[1][r];
    }
#pragma unroll
    for (int m = 1; m <= 8; m <<= 1) {
#pragma unroll
      for (int r = 0; r < 4; r++) {
        s[r]  += __shfl_xor(s[r], m, 64);
        s2[r] += __shfl_xor(s2[r], m, 64);
      }
    }
    float mu[4], rstd[4];
#pragma unroll
    for (int r = 0; r < 4; r++) {
      mu[r] = s[r] * (1.f / 32.f);
      const float var = fmaxf(s2[r] * (1.f / 32.f) - mu[r] * mu[r], 0.f);
      rstd[r] = rsqrtf(var + 1e-6f);
    }

    // z = LN2(y) -> bf16 -> LDS (D-layout write), read back as A-frag
#pragma unroll
    for (int t = 0; t < 2; t++) {
#pragma unroll
      for (int r = 0; r < 4; r++) {
        const float zz = (y[t][r] - mu[r]) * rstd[r] * n2wv[t] + n2bv[t];
        tbuf[wv][4 * lq + r][lr + 16 * t] = f2bf(zz);
      }
    }
    const short8 zf = *(const short8*)&tbuf[wv][lr][8 * lq];

    // conv4: 16 pix x 64 outs
    f32x4 e0 = __builtin_amdgcn_mfma_f32_16x16x32_bf16(zf, w4f[0], zero, 0, 0, 0);
    f32x4 e1 = __builtin_amdgcn_mfma_f32_16x16x32_bf16(zf, w4f[1], zero, 0, 0, 0);
    f32x4 e2 = __builtin_amdgcn_mfma_f32_16x16x32_bf16(zf, w4f[2], zero, 0, 0, 0);
    f32x4 e3 = __builtin_amdgcn_mfma_f32_16x16x32_bf16(zf, w4f[3], zero, 0, 0, 0);

    // SimpleGate: g[o] = (e[o]+b4[o]) * (e[o+32]+b4[o+32]) -> LDS -> A-frag
#pragma unroll
    for (int t = 0; t < 2; t++) {
      const f32x4 ea = t ? e1 : e0;
      const f32x4 eb = t ? e3 : e2;
#pragma unroll
      for (int r = 0; r < 4; r++) {
        const float gg = (ea[r] + b4v[t]) * (eb[r] + b4v[t + 2]);
        tbuf[wv][4 * lq + r][lr + 16 * t] = f2bf(gg);
      }
    }
    const short8 gf = *(const short8*)&tbuf[wv][lr][8 * lq];

    // conv5: 16 pix x 32 outs
    f32x4 f0 = __builtin_amdgcn_mfma_f32_16x16x32_bf16(gf, w5f[0], zero, 0, 0, 0);
    f32x4 f1 = __builtin_amdgcn_mfma_f32_16x16x32_bf16(gf, w5f[1], zero, 0, 0, 0);

    // out = y + (conv5 + b5)*gamma  (same D-layout as y -> float4 store)
#pragma unroll
    for (int t = 0; t < 2; t++) {
      const f32x4 ff = t ? f1 : f0;
      f32x4 ov;
#pragma unroll
      for (int r = 0; r < 4; r++) ov[r] = y[t][r] + (ff[r] + b5v[t]) * gav[t];
      *(f32x4*)(out + ib + (((size_t)(lr + 16 * t)) << 16) + P0 + 4 * lq) = ov;
    }
  }
}

extern "C" void kernel_launch(void* const* d_in, const int* in_sizes, int n_in,
                              void* d_out, int out_size, void* d_ws, size_t ws_size,
                              hipStream_t stream) {
  (void)in_sizes; (void)n_in; (void)out_size; (void)ws_size;
  const float* inp = (const float*)d_in[0];
  WPtrs p;
  p.w1 = (const float*)d_in[1];  p.b1 = (const float*)d_in[2];
  p.w2 = (const float*)d_in[3];  p.b2 = (const float*)d_in[4];
  p.w3 = (const float*)d_in[5];  p.b3 = (const float*)d_in[6];
  p.w4 = (const float*)d_in[7];  p.b4 = (const float*)d_in[8];
  p.w5 = (const float*)d_in[9];  p.b5 = (const float*)d_in[10];
  p.n1w = (const float*)d_in[11]; p.n1b = (const float*)d_in[12];
  p.n2w = (const float*)d_in[13]; p.n2b = (const float*)d_in[14];
  p.scaw = (const float*)d_in[15]; p.scab = (const float*)d_in[16];
  p.beta = (const float*)d_in[17]; p.gamma = (const float*)d_in[18];

  float* wf = (float*)d_ws;
  float* x3 = (float*)d_out;   // fp32 x3 lives in d_out (exact 128 MiB fit)
  float* out = (float*)d_out;

  k_pack<<<dim3(128), dim3(256), 0, stream>>>(p, wf);
  k_front<<<dim3(256, 16), dim3(256), 0, stream>>>(inp, wf, x3, wf + OFF_PART);
  k_sca<<<dim3(16), dim3(256), 0, stream>>>(wf);
  k_back<<<dim3(256, 16), dim3(256), 0, stream>>>(inp, x3, wf, out);
}

// Round 7
// 507.653 us; speedup vs baseline: 3.4088x; 1.0134x over previous
//
#include <hip/hip_runtime.h>
#include <hip/hip_bf16.h>

typedef unsigned short u16;
typedef unsigned int   u32;
typedef __attribute__((ext_vector_type(8))) short short8;  // 8 x bf16 MFMA frag
typedef __attribute__((ext_vector_type(4))) float f32x4;   // MFMA accumulator
typedef __attribute__((ext_vector_type(2))) float f32x2;   // for v_pk_fma_f32

#define DI static __device__ __forceinline__

// ---- problem constants ----
// B=16, C=32, DW=64, H=256, W=256, HW=65536. ALL inputs fp32, output fp32.
// x3 intermediate (128 MiB fp32) lives in d_out: k_front writes, k_back
// consumes and overwrites with the final output.
//
// [R6->R7: VALU instruction diet. R6 counters: k_front 225 us, VALUBusy 52%,
//  Occ 32% (3-block LDS ceiling reached) -> now VALU-ISSUE-bound (~107 us of
//  pure VALU per model, matches 225*0.52). Cuts: (1) dwconv taps via
//  v_pk_fma_f32 (float2 elementwise_fma; lo/hi gate halves share geometry,
//  4->3 ops/tap); (2) all bf16 packing via v_cvt_pk_bf16_f32
//  (__float22bfloat162_rn, ~10 ops/pair -> 1, same RNE bits); (3) same cvt
//  in k_back's serial chains (latency-bound; shortens dependency chains).
//  Bank conflicts 2.1M cyc ~ 3 us device-wide: ignored as negligible.]

// ---- workspace layout (float offsets) ----
static constexpr int OFF_SSUM = 0;        // (unused; kept for layout)
static constexpr int OFF_SCALE = 512;     // 512
static constexpr int OFF_W1 = 1024;       // 16*64*32 = 32768
static constexpr int OFF_B1 = 33792;      // 1024
static constexpr int OFF_W2 = 34816;      // 16*64*9 = 9216
static constexpr int OFF_B2 = 44032;      // 1024
static constexpr int OFF_W3 = 45056;      // 16*32*32 = 16384
static constexpr int OFF_B3 = 61440;      // 512
static constexpr int OFF_W4 = 61952;      // 32768
static constexpr int OFF_B4 = 94720;      // 1024
static constexpr int OFF_W5 = 95744;      // 16384
static constexpr int OFF_B5 = 112128;     // 512
static constexpr int OFF_N1W = 112640;    // 32
static constexpr int OFF_N1B = 112672;    // 32
static constexpr int OFF_N2W = 112704;    // 32
static constexpr int OFF_N2B = 112736;    // 32
static constexpr int OFF_SCAW = 112768;   // 1024
static constexpr int OFF_SCAB = 113792;   // 32
static constexpr int OFF_BETA = 113824;   // 32
static constexpr int OFF_GAMMA = 113856;  // 32
static constexpr int OFF_PART = 113920;   // 4096 blocks * 32 ch = 131072 floats

// packed bf16x2 via v_cvt_pk_bf16_f32 (RNE, same bits as hand-rolled f2bf)
DI u32 pkbf2(float lo, float hi) {
  union { __hip_bfloat162 h; u32 u; } cv;
  cv.h = __float22bfloat162_rn(make_float2(lo, hi));
  return cv.u;
}

struct WPtrs {
  const float *w1, *b1, *w2, *b2, *w3, *b3, *w4, *b4, *w5, *b5;
  const float *n1w, *n1b, *n2w, *n2b, *scaw, *scab, *beta, *gamma;
};

union S8U { u32 w[4]; short8 v; };

// convert 8 consecutive fp32 weights to a bf16x8 MFMA fragment
DI short8 wfrag(const float* wp) {
  S8U u;
#pragma unroll
  for (int q = 0; q < 4; q++) u.w[q] = pkbf2(wp[2 * q], wp[2 * q + 1]);
  return u.v;
}

DI void cpy_seg(float* dst, const float* src, int n, int tid, int stride) {
  for (int i = tid; i < n; i += stride) dst[i] = src[i];
}

// ---- K0: gather all weights into contiguous fp32 ws ----
__global__ __launch_bounds__(256) void k_pack(WPtrs p, float* __restrict__ wf) {
  const int tid = blockIdx.x * 256 + threadIdx.x;
  const int stride = gridDim.x * 256;
  cpy_seg(wf + OFF_W1, p.w1, 32768, tid, stride);
  cpy_seg(wf + OFF_B1, p.b1, 1024, tid, stride);
  cpy_seg(wf + OFF_W2, p.w2, 9216, tid, stride);
  cpy_seg(wf + OFF_B2, p.b2, 1024, tid, stride);
  cpy_seg(wf + OFF_W3, p.w3, 16384, tid, stride);
  cpy_seg(wf + OFF_B3, p.b3, 512, tid, stride);
  cpy_seg(wf + OFF_W4, p.w4, 32768, tid, stride);
  cpy_seg(wf + OFF_B4, p.b4, 1024, tid, stride);
  cpy_seg(wf + OFF_W5, p.w5, 16384, tid, stride);
  cpy_seg(wf + OFF_B5, p.b5, 512, tid, stride);
  cpy_seg(wf + OFF_N1W, p.n1w, 32, tid, stride);
  cpy_seg(wf + OFF_N1B, p.n1b, 32, tid, stride);
  cpy_seg(wf + OFF_N2W, p.n2w, 32, tid, stride);
  cpy_seg(wf + OFF_N2B, p.n2b, 32, tid, stride);
  cpy_seg(wf + OFF_SCAW, p.scaw, 1024, tid, stride);
  cpy_seg(wf + OFF_SCAB, p.scab, 32, tid, stride);
  cpy_seg(wf + OFF_BETA, p.beta, 32, tid, stride);
  cpy_seg(wf + OFF_GAMMA, p.gamma, 32, tid, stride);
}

// ---- K1: (A) LN1 -> bf16 LDS tile; two passes of {(B) conv1x1 via MFMA;
// (C) dwconv3x3 + SimpleGate}. Per-block SE partials, no atomics. ----
__global__ __launch_bounds__(256) void k_front(const float* __restrict__ inp,
                                               const float* __restrict__ wf,
                                               float* __restrict__ x3,
                                               float* __restrict__ part) {
  const int tid = threadIdx.x;
  const int b = blockIdx.y;
  const int tile = blockIdx.x;        // 8 tiles in x, 32 in y
  const int tx = tile & 7, ty = tile >> 3;
  const int gx0 = tx * 32 - 1, gy0 = ty * 8 - 1;

  __shared__ u16 xln[352][40];   // LN'd input, bf16, pad-40 rows (28160 B)
  __shared__ u32 x1h[16][341];   // conv1 out half, packed pairs  (21824 B)
  __shared__ float psum[4][32];  // per-wave SE partials           (512 B)

  const float* w1 = wf + OFF_W1 + b * 2048;
  const float* b1 = wf + OFF_B1 + b * 64;
  const float* n1w = wf + OFF_N1W;
  const float* n1b = wf + OFF_N1B;

  // ---- stage A: LN per halo pixel -> bf16 -> xln ----
#pragma unroll 1
  for (int idx = tid; idx < 352; idx += 256) {
    const int py = idx / 34;
    const int px = idx - py * 34;
    const int gy = gy0 + py, gx = gx0 + px;
    u32 pk[16];
    if (idx >= 340 || (u32)gy >= 256u || (u32)gx >= 256u) {
#pragma unroll
      for (int j = 0; j < 16; j++) pk[j] = 0u;
    } else {
      const float* src = inp + (((size_t)(b * 32)) << 16) + (gy << 8) + gx;
      float x[32];
      float s = 0.f, s2 = 0.f;
#pragma unroll
      for (int c = 0; c < 32; c++) {
        float v = src[(size_t)c << 16];
        x[c] = v; s += v; s2 += v * v;
      }
      const float mu = s * (1.f / 32.f);
      const float var = fmaxf(s2 * (1.f / 32.f) - mu * mu, 0.f);
      const float rstd = rsqrtf(var + 1e-6f);
#pragma unroll
      for (int j = 0; j < 16; j++) {
        const float lo = (x[2 * j] - mu) * rstd * n1w[2 * j] + n1b[2 * j];
        const float hi = (x[2 * j + 1] - mu) * rstd * n1w[2 * j + 1] + n1b[2 * j + 1];
        pk[j] = pkbf2(lo, hi);
      }
    }
    u32* row = (u32*)&xln[idx][0];  // 80 B rows -> always 16B aligned
#pragma unroll
    for (int q = 0; q < 4; q++)
      *(uint4*)(row + 4 * q) = make_uint4(pk[4 * q], pk[4 * q + 1], pk[4 * q + 2], pk[4 * q + 3]);
  }

  // ---- W1 B-frags + biases ----
  const int lane = tid & 63;
  const int wv = tid >> 6;
  const int lr = lane & 15;
  const int lq = lane >> 4;

  short8 w1f[4];
#pragma unroll
  for (int t = 0; t < 4; t++) w1f[t] = wfrag(w1 + (t * 16 + lr) * 32 + 8 * lq);
  float b1v[4];
#pragma unroll
  for (int t = 0; t < 4; t++) b1v[t] = b1[t * 16 + lr];

  // stage-C geometry
  const int cpx = tid & 31, cpy = tid >> 5;  // 32x8 interior
  const int p = (cpy + 1) * 34 + (cpx + 1);
  const int gpix = ((ty * 8 + cpy) << 8) + (tx * 32 + cpx);
  const float* w2 = wf + OFF_W2 + b * 576;
  const float* b2 = wf + OFF_B2 + b * 64;
  float* ob = x3 + (((size_t)(b * 32)) << 16) + gpix;

  __syncthreads();

  const f32x4 zero = {0.f, 0.f, 0.f, 0.f};

#pragma unroll 1
  for (int ph = 0; ph < 2; ph++) {
    // ---- stage B (pass ph): conv1 channels {ph*16+lr, ph*16+lr+32} ----
#pragma unroll 1
    for (int g = wv; g < 22; g += 4) {
      const short8 af = *(const short8*)&xln[16 * g + lr][8 * lq];
      f32x4 dA = __builtin_amdgcn_mfma_f32_16x16x32_bf16(af, w1f[ph], zero, 0, 0, 0);
      f32x4 dB = __builtin_amdgcn_mfma_f32_16x16x32_bf16(af, w1f[ph + 2], zero, 0, 0, 0);
#pragma unroll
      for (int r = 0; r < 4; r++) {
        const int pix = 16 * g + 4 * lq + r;
        if (pix < 340) {
          const int py = pix / 34;
          const int px = pix - 34 * py;
          const int gy = gy0 + py, gx = gx0 + px;
          u32 v = 0u;
          if (((u32)gy < 256u) & ((u32)gx < 256u))
            v = pkbf2(dA[r] + b1v[ph], dB[r] + b1v[ph + 2]);
          x1h[lr][pix] = v;
        }
      }
    }
    __syncthreads();

    // ---- stage C (pass ph): dwconv3x3 + gate, packed v_pk_fma_f32 taps ----
#pragma unroll 4
    for (int cc = 0; cc < 16; cc++) {
      const int c = ph * 16 + cc;
      f32x2 acc = {b2[c], b2[c + 32]};
      const int offs[9] = {-35, -34, -33, -1, 0, 1, 33, 34, 35};
#pragma unroll
      for (int k = 0; k < 9; k++) {
        const u32 u = x1h[cc][p + offs[k]];
        const f32x2 val = {__uint_as_float(u << 16), __uint_as_float(u & 0xffff0000u)};
        const f32x2 wgt = {w2[c * 9 + k], w2[(c + 32) * 9 + k]};
        acc = __builtin_elementwise_fma(val, wgt, acc);
      }
      const float v = acc.x * acc.y;  // SimpleGate
      ob[(size_t)c << 16] = v;
      float r = v;
#pragma unroll
      for (int off = 32; off > 0; off >>= 1) r += __shfl_xor(r, off, 64);
      if ((tid & 63) == 0) psum[wv][c] = r;
    }
    __syncthreads();  // protects x1h reuse (ph=0) / psum completeness (ph=1)
  }

  // one plain coalesced 32-float store per block
  if (tid < 32) {
    const float t4 = psum[0][tid] + psum[1][tid] + psum[2][tid] + psum[3][tid];
    part[(((b << 8) + tile) << 5) + tid] = t4;
  }
}

// ---- K2: SE head: reduce 256 per-tile partials -> mean -> 32x32 matmul ----
__global__ __launch_bounds__(256) void k_sca(float* __restrict__ wf) {
  const int b = blockIdx.x;
  const int tid = threadIdx.x;
  const int q = tid >> 5, c = tid & 31;
  __shared__ float l[8][32];
  __shared__ float sv[32];
  const float* part = wf + OFF_PART + b * 8192;  // 256 tiles * 32 ch
  float a = 0.f;
#pragma unroll 4
  for (int t = q; t < 256; t += 8) a += part[t * 32 + c];
  l[q][c] = a;
  __syncthreads();
  if (tid < 32) {
    float s = 0.f;
#pragma unroll
    for (int qq = 0; qq < 8; qq++) s += l[qq][tid];
    sv[tid] = s * (1.f / 65536.f);
  }
  __syncthreads();
  if (tid < 32) {
    const float* sw = wf + OFF_SCAW;
    float acc = wf[OFF_SCAB + tid];
#pragma unroll
    for (int cc = 0; cc < 32; cc++) acc += sv[cc] * sw[tid * 32 + cc];
    wf[OFF_SCALE + b * 32 + tid] = acc;
  }
}

// ---- K3 (MFMA): scale*x3 -> conv3 -> beta-res -> LN2 -> conv4 -> SG -> conv5
//                 -> gamma-res.  Same loop structure as R2-R6; bf16 packing
//                 sites converted to v_cvt_pk_bf16_f32 (shorter serial chains).
__global__ __launch_bounds__(256) void k_back(const float* __restrict__ inp,
                                              const float* x3,
                                              const float* __restrict__ wf,
                                              float* out) {
  const int tid = threadIdx.x;
  const int b = blockIdx.y;
  const int wv = tid >> 6;       // 4 waves/block
  const int lane = tid & 63;
  const int lr = lane & 15;
  const int lq = lane >> 4;

  __shared__ u16 tbuf[4][16][40];  // per-wave transpose tile (5120 B)

  const size_t ib = ((size_t)(b * 32)) << 16;
  const float* w3 = wf + OFF_W3 + b * 1024;
  const float* w4 = wf + OFF_W4 + b * 2048;
  const float* w5 = wf + OFF_W5 + b * 1024;

  short8 w3f[2], w4f[4], w5f[2];
#pragma unroll
  for (int t = 0; t < 2; t++) w3f[t] = wfrag(w3 + (t * 16 + lr) * 32 + 8 * lq);
#pragma unroll
  for (int t = 0; t < 4; t++) w4f[t] = wfrag(w4 + (t * 16 + lr) * 32 + 8 * lq);
#pragma unroll
  for (int t = 0; t < 2; t++) w5f[t] = wfrag(w5 + (t * 16 + lr) * 32 + 8 * lq);

  float scv[8];  // SE scale for this lane's A-frag channels
#pragma unroll
  for (int j = 0; j < 8; j++) scv[j] = wf[OFF_SCALE + b * 32 + 8 * lq + j];

  float b3v[2], bev[2], n2wv[2], n2bv[2], b5v[2], gav[2], b4v[4];
#pragma unroll
  for (int t = 0; t < 2; t++) {
    b3v[t]  = wf[OFF_B3 + b * 32 + lr + 16 * t];
    bev[t]  = wf[OFF_BETA + lr + 16 * t];
    n2wv[t] = wf[OFF_N2W + lr + 16 * t];
    n2bv[t] = wf[OFF_N2B + lr + 16 * t];
    b5v[t]  = wf[OFF_B5 + b * 32 + lr + 16 * t];
    gav[t]  = wf[OFF_GAMMA + lr + 16 * t];
  }
#pragma unroll
  for (int t = 0; t < 4; t++) b4v[t] = wf[OFF_B4 + b * 64 + lr + 16 * t];

  const f32x4 zero = {0.f, 0.f, 0.f, 0.f};

#pragma unroll 1
  for (int it = 0; it < 4; it++) {
    const int P0 = blockIdx.x * 256 + wv * 64 + it * 16;

    // A-frag of SE-scaled x3 (cvt_pk per channel pair)
    S8U xa;
#pragma unroll
    for (int q = 0; q < 4; q++) {
      const float v0 = x3[ib + (((size_t)(8 * lq + 2 * q)) << 16) + P0 + lr] * scv[2 * q];
      const float v1 = x3[ib + (((size_t)(8 * lq + 2 * q + 1)) << 16) + P0 + lr] * scv[2 * q + 1];
      xa.w[q] = pkbf2(v0, v1);
    }
    const short8 xaf = xa.v;

    // conv3: 16 pix x 32 outs
    f32x4 d0 = __builtin_amdgcn_mfma_f32_16x16x32_bf16(xaf, w3f[0], zero, 0, 0, 0);
    f32x4 d1 = __builtin_amdgcn_mfma_f32_16x16x32_bf16(xaf, w3f[1], zero, 0, 0, 0);

    // y = inp + (conv3 + b3)*beta ; LN2 stats via 16-lane shfl_xor reduce
    float y[2][4], s[4], s2[4];
#pragma unroll
    for (int t = 0; t < 2; t++) {
      const f32x4 iv = *(const f32x4*)(inp + ib + (((size_t)(lr + 16 * t)) << 16) + P0 + 4 * lq);
      const f32x4 dd = t ? d1 : d0;
#pragma unroll
      for (int r = 0; r < 4; r++) y[t][r] = iv[r] + (dd[r] + b3v[t]) * bev[t];
    }
#pragma unroll
    for (int r = 0; r < 4; r++) {
      s[r]  = y[0][r] + y[1][r];
      s2[r] = y[0][r] * y[0][r] + y[1][r] * y[1][r];
    }
#pragma unroll
    for (int m = 1; m <= 8; m <<= 1) {
#pragma unroll
      for (int r = 0; r < 4; r++) {
        s[r]  += __shfl_xor(s[r], m, 64);
        s2[r] += __shfl_xor(s2[r], m, 64);
      }
    }
    float mu[4], rstd[4];
#pragma unroll
    for (int r = 0; r < 4; r++) {
      mu[r] = s[r] * (1.f / 32.f);
      const float var = fmaxf(s2[r] * (1.f / 32.f) - mu[r] * mu[r], 0.f);
      rstd[r] = rsqrtf(var + 1e-6f);
    }

    // z = LN2(y) -> bf16 (cvt_pk) -> LDS (D-layout), read back as A-frag
#pragma unroll
    for (int r = 0; r < 4; r++) {
      const float z0 = (y[0][r] - mu[r]) * rstd[r] * n2wv[0] + n2bv[0];
      const float z1 = (y[1][r] - mu[r]) * rstd[r] * n2wv[1] + n2bv[1];
      const u32 pk = pkbf2(z0, z1);
      tbuf[wv][4 * lq + r][lr] = (u16)pk;
      tbuf[wv][4 * lq + r][lr + 16] = (u16)(pk >> 16);
    }
    const short8 zf = *(const short8*)&tbuf[wv][lr][8 * lq];

    // conv4: 16 pix x 64 outs
    f32x4 e0 = __builtin_amdgcn_mfma_f32_16x16x32_bf16(zf, w4f[0], zero, 0, 0, 0);
    f32x4 e1 = __builtin_amdgcn_mfma_f32_16x16x32_bf16(zf, w4f[1], zero, 0, 0, 0);
    f32x4 e2 = __builtin_amdgcn_mfma_f32_16x16x32_bf16(zf, w4f[2], zero, 0, 0, 0);
    f32x4 e3 = __builtin_amdgcn_mfma_f32_16x16x32_bf16(zf, w4f[3], zero, 0, 0, 0);

    // SimpleGate -> bf16 (cvt_pk) -> LDS -> A-frag
#pragma unroll
    for (int r = 0; r < 4; r++) {
      const float g0 = (e0[r] + b4v[0]) * (e2[r] + b4v[2]);
      const float g1 = (e1[r] + b4v[1]) * (e3[r] + b4v[3]);
      const u32 pk = pkbf2(g0, g1);
      tbuf[wv][4 * lq + r][lr] = (u16)pk;
      tbuf[wv][4 * lq + r][lr + 16] = (u16)(pk >> 16);
    }
    const short8 gf = *(const short8*)&tbuf[wv][lr][8 * lq];

    // conv5: 16 pix x 32 outs
    f32x4 f0 = __builtin_amdgcn_mfma_f32_16x16x32_bf16(gf, w5f[0], zero, 0, 0, 0);
    f32x4 f1 = __builtin_amdgcn_mfma_f32_16x16x32_bf16(gf, w5f[1], zero, 0, 0, 0);

    // out = y + (conv5 + b5)*gamma  (same D-layout as y -> float4 store)
#pragma unroll
    for (int t = 0; t < 2; t++) {
      const f32x4 ff = t ? f1 : f0;
      f32x4 ov;
#pragma unroll
      for (int r = 0; r < 4; r++) ov[r] = y[t][r] + (ff[r] + b5v[t]) * gav[t];
      *(f32x4*)(out + ib + (((size_t)(lr + 16 * t)) << 16) + P0 + 4 * lq) = ov;
    }
  }
}

extern "C" void kernel_launch(void* const* d_in, const int* in_sizes, int n_in,
                              void* d_out, int out_size, void* d_ws, size_t ws_size,
                              hipStream_t stream) {
  (void)in_sizes; (void)n_in; (void)out_size; (void)ws_size;
  const float* inp = (const float*)d_in[0];
  WPtrs p;
  p.w1 = (const float*)d_in[1];  p.b1 = (const float*)d_in[2];
  p.w2 = (const float*)d_in[3];  p.b2 = (const float*)d_in[4];
  p.w3 = (const float*)d_in[5];  p.b3 = (const float*)d_in[6];
  p.w4 = (const float*)d_in[7];  p.b4 = (const float*)d_in[8];
  p.w5 = (const float*)d_in[9];  p.b5 = (const float*)d_in[10];
  p.n1w = (const float*)d_in[11]; p.n1b = (const float*)d_in[12];
  p.n2w = (const float*)d_in[13]; p.n2b = (const float*)d_in[14];
  p.scaw = (const float*)d_in[15]; p.scab = (const float*)d_in[16];
  p.beta = (const float*)d_in[17]; p.gamma = (const float*)d_in[18];

  float* wf = (float*)d_ws;
  float* x3 = (float*)d_out;   // fp32 x3 lives in d_out (exact 128 MiB fit)
  float* out = (float*)d_out;

  k_pack<<<dim3(128), dim3(256), 0, stream>>>(p, wf);
  k_front<<<dim3(256, 16), dim3(256), 0, stream>>>(inp, wf, x3, wf + OFF_PART);
  k_sca<<<dim3(16), dim3(256), 0, stream>>>(wf);
  k_back<<<dim3(256, 16), dim3(256), 0, stream>>>(inp, x3, wf, out);
}